// Round 10
// baseline (1053.583 us; speedup 1.0000x reference)
//
#include <hip/hip_runtime.h>
#include <math.h>

// ---------------------------------------------------------------------------
// STDF forward, round 9: (a) conv3db LDS row stride 10->12 (uniform 2-way bank
// cover, removes the +2cyc/read conflict tax); (b) deform conv rebuilt with
// scalar-weight path (w_dc pre-transposed to [ck][64], wave-uniform s_load)
// + 4-way co split (16 co/thread, 800 blocks). Rest identical to round 8.
// ---------------------------------------------------------------------------

#define TPB 256

static inline int nblk(long long total) { return (int)((total + TPB - 1) / TPB); }
static inline int bpc_of(int H, int nq) { return (H * nq + TPB - 1) / TPB; }

// ---------------- 3x3 conv2d, stride 1, 4 outputs/thread, block-uniform co --
template <int RELU, int HAS_RES>
__global__ __launch_bounds__(TPB) void conv2d_t4_k(
    const float* __restrict__ in, const float* __restrict__ w,
    const float* __restrict__ bias, const float* __restrict__ res,
    float* __restrict__ out, int B, int Ci, int H, int W, int Co, int BPC) {
    __shared__ float ws_w[32 * 9];
    int co = (blockIdx.x / BPC) % Co;
    int b  = blockIdx.x / (BPC * Co);
    for (int i = threadIdx.x; i < Ci * 9; i += TPB)
        ws_w[i] = w[(size_t)co * Ci * 9 + i];
    __syncthreads();
    int nq = W >> 2;
    int r = (blockIdx.x % BPC) * TPB + threadIdx.x;
    if (r >= H * nq) return;
    int q = r % nq, ho = r / nq;
    int wb = q * 4;
    float bv = bias[co];
    float a0 = bv, a1 = bv, a2 = bv, a3 = bv;
    const float* ipb = in + (size_t)b * Ci * H * W;
    for (int ci = 0; ci < Ci; ++ci) {
        const float* ip = ipb + (size_t)ci * H * W;
        const float* wc = ws_w + ci * 9;
#pragma unroll
        for (int kh = 0; kh < 3; ++kh) {
            int y = ho - 1 + kh;
            if (y < 0 || y >= H) continue;
            const float* row = ip + (size_t)y * W + wb;
            float4 xv = *(const float4*)row;
            float xm = (wb > 0) ? row[-1] : 0.f;
            float xp = (wb + 4 < W) ? row[4] : 0.f;
            float w0 = wc[kh * 3], w1 = wc[kh * 3 + 1], w2 = wc[kh * 3 + 2];
            a0 += xm   * w0 + xv.x * w1 + xv.y * w2;
            a1 += xv.x * w0 + xv.y * w1 + xv.z * w2;
            a2 += xv.y * w0 + xv.z * w1 + xv.w * w2;
            a3 += xv.z * w0 + xv.w * w1 + xp   * w2;
        }
    }
    size_t o = ((size_t)(b * Co + co) * H + ho) * W + wb;
    if (HAS_RES) {
        float4 rv = *(const float4*)(res + o);
        a0 += rv.x; a1 += rv.y; a2 += rv.z; a3 += rv.w;
    }
    if (RELU) { a0 = fmaxf(a0, 0.f); a1 = fmaxf(a1, 0.f); a2 = fmaxf(a2, 0.f); a3 = fmaxf(a3, 0.f); }
    *(float4*)(out + o) = make_float4(a0, a1, a2, a3);
}

// ------- 3x3 conv2d, stride 1, 4 outputs x 4 co per thread -----------------
template <int RELU, int HAS_RES>
__global__ __launch_bounds__(TPB) void conv2d_c4_k(
    const float* __restrict__ in, const float* __restrict__ w,
    const float* __restrict__ bias, const float* __restrict__ res,
    float* __restrict__ out, int B, int Ci, int H, int W, int Co, int COG, int BPC) {
    __shared__ float ws_w[4 * 32 * 9];
    int cog = (blockIdx.x / BPC) % COG;
    int b   = blockIdx.x / (BPC * COG);
    int co0 = cog * 4;
    int nw = Ci * 9;
    for (int i = threadIdx.x; i < 4 * nw; i += TPB) {
        int cr = i / nw; int co = co0 + cr;
        ws_w[i] = (co < Co) ? w[(size_t)co * nw + (i - cr * nw)] : 0.f;
    }
    __syncthreads();
    int nq = W >> 2;
    int r = (blockIdx.x % BPC) * TPB + threadIdx.x;
    if (r >= H * nq) return;
    int q = r % nq, ho = r / nq;
    int wb = q * 4;
    float a[4][4];
#pragma unroll
    for (int cr = 0; cr < 4; ++cr) {
        float bv = (co0 + cr < Co) ? bias[co0 + cr] : 0.f;
        a[cr][0] = bv; a[cr][1] = bv; a[cr][2] = bv; a[cr][3] = bv;
    }
    const float* ipb = in + (size_t)b * Ci * H * W;
    for (int ci = 0; ci < Ci; ++ci) {
        const float* ip = ipb + (size_t)ci * H * W;
#pragma unroll
        for (int kh = 0; kh < 3; ++kh) {
            int y = ho - 1 + kh;
            if (y < 0 || y >= H) continue;
            const float* row = ip + (size_t)y * W + wb;
            float4 xv = *(const float4*)row;
            float x_[6];
            x_[0] = (wb > 0) ? row[-1] : 0.f;
            x_[1] = xv.x; x_[2] = xv.y; x_[3] = xv.z; x_[4] = xv.w;
            x_[5] = (wb + 4 < W) ? row[4] : 0.f;
#pragma unroll
            for (int cr = 0; cr < 4; ++cr) {
                const float* wc = ws_w + cr * nw + ci * 9 + kh * 3;
                float w0 = wc[0], w1 = wc[1], w2 = wc[2];
                a[cr][0] += x_[0] * w0 + x_[1] * w1 + x_[2] * w2;
                a[cr][1] += x_[1] * w0 + x_[2] * w1 + x_[3] * w2;
                a[cr][2] += x_[2] * w0 + x_[3] * w1 + x_[4] * w2;
                a[cr][3] += x_[3] * w0 + x_[4] * w1 + x_[5] * w2;
            }
        }
    }
#pragma unroll
    for (int cr = 0; cr < 4; ++cr) {
        int co = co0 + cr;
        if (co >= Co) break;
        size_t o = ((size_t)(b * Co + co) * H + ho) * W + wb;
        float a0 = a[cr][0], a1 = a[cr][1], a2 = a[cr][2], a3 = a[cr][3];
        if (HAS_RES) {
            float4 rv = *(const float4*)(res + o);
            a0 += rv.x; a1 += rv.y; a2 += rv.z; a3 += rv.w;
        }
        if (RELU) { a0 = fmaxf(a0, 0.f); a1 = fmaxf(a1, 0.f); a2 = fmaxf(a2, 0.f); a3 = fmaxf(a3, 0.f); }
        *(float4*)(out + o) = make_float4(a0, a1, a2, a3);
    }
}

// ------- 3x3 conv2d, stride 1, 4 outputs x 8 co per thread (for w_om) ------
template <int RELU>
__global__ __launch_bounds__(TPB) void conv2d_c8_k(
    const float* __restrict__ in, const float* __restrict__ w,
    const float* __restrict__ bias, float* __restrict__ out,
    int B, int Ci, int H, int W, int Co, int COG, int BPC) {
    __shared__ __align__(16) float4 wsa[32 * 9];
    __shared__ __align__(16) float4 wsb[32 * 9];
    int cog = (blockIdx.x / BPC) % COG;
    int b   = blockIdx.x / (BPC * COG);
    int co0 = cog * 8;
    int nw = Ci * 9;
    for (int i = threadIdx.x; i < nw; i += TPB) {
        float4 v, u;
        v.x = (co0 + 0 < Co) ? w[(size_t)(co0 + 0) * nw + i] : 0.f;
        v.y = (co0 + 1 < Co) ? w[(size_t)(co0 + 1) * nw + i] : 0.f;
        v.z = (co0 + 2 < Co) ? w[(size_t)(co0 + 2) * nw + i] : 0.f;
        v.w = (co0 + 3 < Co) ? w[(size_t)(co0 + 3) * nw + i] : 0.f;
        u.x = (co0 + 4 < Co) ? w[(size_t)(co0 + 4) * nw + i] : 0.f;
        u.y = (co0 + 5 < Co) ? w[(size_t)(co0 + 5) * nw + i] : 0.f;
        u.z = (co0 + 6 < Co) ? w[(size_t)(co0 + 6) * nw + i] : 0.f;
        u.w = (co0 + 7 < Co) ? w[(size_t)(co0 + 7) * nw + i] : 0.f;
        wsa[i] = v; wsb[i] = u;
    }
    __syncthreads();
    int nq = W >> 2;
    int r = (blockIdx.x % BPC) * TPB + threadIdx.x;
    if (r >= H * nq) return;
    int q = r % nq, ho = r / nq;
    int wb = q * 4;
    float a[8][4];
#pragma unroll
    for (int cr = 0; cr < 8; ++cr) {
        float bv = (co0 + cr < Co) ? bias[co0 + cr] : 0.f;
        a[cr][0] = bv; a[cr][1] = bv; a[cr][2] = bv; a[cr][3] = bv;
    }
    const float* ipb = in + (size_t)b * Ci * H * W;
    for (int ci = 0; ci < Ci; ++ci) {
        const float* ip = ipb + (size_t)ci * H * W;
#pragma unroll
        for (int kh = 0; kh < 3; ++kh) {
            int y = ho - 1 + kh;
            if (y < 0 || y >= H) continue;
            const float* row = ip + (size_t)y * W + wb;
            float4 xv = *(const float4*)row;
            float x_[6];
            x_[0] = (wb > 0) ? row[-1] : 0.f;
            x_[1] = xv.x; x_[2] = xv.y; x_[3] = xv.z; x_[4] = xv.w;
            x_[5] = (wb + 4 < W) ? row[4] : 0.f;
#pragma unroll
            for (int kw = 0; kw < 3; ++kw) {
                float4 wv = wsa[ci * 9 + kh * 3 + kw];
                float4 wu = wsb[ci * 9 + kh * 3 + kw];
                float x0 = x_[kw], x1 = x_[kw + 1], x2 = x_[kw + 2], x3 = x_[kw + 3];
                a[0][0] += x0 * wv.x; a[0][1] += x1 * wv.x; a[0][2] += x2 * wv.x; a[0][3] += x3 * wv.x;
                a[1][0] += x0 * wv.y; a[1][1] += x1 * wv.y; a[1][2] += x2 * wv.y; a[1][3] += x3 * wv.y;
                a[2][0] += x0 * wv.z; a[2][1] += x1 * wv.z; a[2][2] += x2 * wv.z; a[2][3] += x3 * wv.z;
                a[3][0] += x0 * wv.w; a[3][1] += x1 * wv.w; a[3][2] += x2 * wv.w; a[3][3] += x3 * wv.w;
                a[4][0] += x0 * wu.x; a[4][1] += x1 * wu.x; a[4][2] += x2 * wu.x; a[4][3] += x3 * wu.x;
                a[5][0] += x0 * wu.y; a[5][1] += x1 * wu.y; a[5][2] += x2 * wu.y; a[5][3] += x3 * wu.y;
                a[6][0] += x0 * wu.z; a[6][1] += x1 * wu.z; a[6][2] += x2 * wu.z; a[6][3] += x3 * wu.z;
                a[7][0] += x0 * wu.w; a[7][1] += x1 * wu.w; a[7][2] += x2 * wu.w; a[7][3] += x3 * wu.w;
            }
        }
    }
#pragma unroll
    for (int cr = 0; cr < 8; ++cr) {
        int co = co0 + cr;
        if (co >= Co) break;
        size_t o = ((size_t)(b * Co + co) * H + ho) * W + wb;
        float a0 = a[cr][0], a1 = a[cr][1], a2 = a[cr][2], a3 = a[cr][3];
        if (RELU) { a0 = fmaxf(a0, 0.f); a1 = fmaxf(a1, 0.f); a2 = fmaxf(a2, 0.f); a3 = fmaxf(a3, 0.f); }
        *(float4*)(out + o) = make_float4(a0, a1, a2, a3);
    }
}

// ------------- 3x3 conv2d over concat of two 32-ch inputs, stride 1, relu ---
__global__ __launch_bounds__(TPB) void conv2d_cat_t4_k(
    const float* __restrict__ in1, const float* __restrict__ in2,
    const float* __restrict__ w, const float* __restrict__ bias,
    float* __restrict__ out, int B, int C1, int C2, int H, int W, int Co, int BPC) {
    __shared__ float ws_w[64 * 9];
    int Ci = C1 + C2;
    int co = (blockIdx.x / BPC) % Co;
    int b  = blockIdx.x / (BPC * Co);
    for (int i = threadIdx.x; i < Ci * 9; i += TPB)
        ws_w[i] = w[(size_t)co * Ci * 9 + i];
    __syncthreads();
    int nq = W >> 2;
    int r = (blockIdx.x % BPC) * TPB + threadIdx.x;
    if (r >= H * nq) return;
    int q = r % nq, ho = r / nq;
    int wb = q * 4;
    float bv = bias[co];
    float a0 = bv, a1 = bv, a2 = bv, a3 = bv;
    for (int ci = 0; ci < Ci; ++ci) {
        const float* ip = (ci < C1)
            ? in1 + ((size_t)(b * C1 + ci)) * H * W
            : in2 + ((size_t)(b * C2 + (ci - C1))) * H * W;
        const float* wc = ws_w + ci * 9;
#pragma unroll
        for (int kh = 0; kh < 3; ++kh) {
            int y = ho - 1 + kh;
            if (y < 0 || y >= H) continue;
            const float* row = ip + (size_t)y * W + wb;
            float4 xv = *(const float4*)row;
            float xm = (wb > 0) ? row[-1] : 0.f;
            float xp = (wb + 4 < W) ? row[4] : 0.f;
            float w0 = wc[kh * 3], w1 = wc[kh * 3 + 1], w2 = wc[kh * 3 + 2];
            a0 += xm   * w0 + xv.x * w1 + xv.y * w2;
            a1 += xv.x * w0 + xv.y * w1 + xv.z * w2;
            a2 += xv.y * w0 + xv.z * w1 + xv.w * w2;
            a3 += xv.z * w0 + xv.w * w1 + xp   * w2;
        }
    }
    size_t o = ((size_t)(b * Co + co) * H + ho) * W + wb;
    *(float4*)(out + o) = make_float4(fmaxf(a0, 0.f), fmaxf(a1, 0.f), fmaxf(a2, 0.f), fmaxf(a3, 0.f));
}

// ------------- 3x3 conv2d, stride 2, 4 outputs/thread, relu ----------------
__global__ __launch_bounds__(TPB) void conv2d_s2_t4_k(
    const float* __restrict__ in, const float* __restrict__ w,
    const float* __restrict__ bias, float* __restrict__ out,
    int B, int Ci, int Hi, int Wi, int Co, int BPC) {
    __shared__ float ws_w[32 * 9];
    int Ho = Hi >> 1, Wo = Wi >> 1;
    int co = (blockIdx.x / BPC) % Co;
    int b  = blockIdx.x / (BPC * Co);
    for (int i = threadIdx.x; i < Ci * 9; i += TPB)
        ws_w[i] = w[(size_t)co * Ci * 9 + i];
    __syncthreads();
    int nq = Wo >> 2;
    int r = (blockIdx.x % BPC) * TPB + threadIdx.x;
    if (r >= Ho * nq) return;
    int q = r % nq, ho = r / nq;
    int wb = q * 4;
    float bv = bias[co];
    float a0 = bv, a1 = bv, a2 = bv, a3 = bv;
    const float* ipb = in + (size_t)b * Ci * Hi * Wi;
    for (int ci = 0; ci < Ci; ++ci) {
        const float* ip = ipb + (size_t)ci * Hi * Wi;
        const float* wc = ws_w + ci * 9;
#pragma unroll
        for (int kh = 0; kh < 3; ++kh) {
            int y = 2 * ho - 1 + kh;
            if (y < 0 || y >= Hi) continue;
            const float* row = ip + (size_t)y * Wi;
            float z0 = (2 * wb - 1 >= 0) ? row[2 * wb - 1] : 0.f;
            float4 za = *(const float4*)(row + 2 * wb);
            float4 zb = *(const float4*)(row + 2 * wb + 4);
            float w0 = wc[kh * 3], w1 = wc[kh * 3 + 1], w2 = wc[kh * 3 + 2];
            a0 += z0   * w0 + za.x * w1 + za.y * w2;
            a1 += za.y * w0 + za.z * w1 + za.w * w2;
            a2 += za.w * w0 + zb.x * w1 + zb.y * w2;
            a3 += zb.y * w0 + zb.z * w1 + zb.w * w2;
        }
    }
    size_t o = ((size_t)(b * Co + co) * Ho + ho) * Wo + wb;
    *(float4*)(out + o) = make_float4(fmaxf(a0, 0.f), fmaxf(a1, 0.f), fmaxf(a2, 0.f), fmaxf(a3, 0.f));
}

// ------------- transposed conv 4x4 stride 2, 4 outputs/thread, relu --------
__global__ __launch_bounds__(TPB) void convt2d_t4_k(
    const float* __restrict__ in, const float* __restrict__ wt,
    const float* __restrict__ bias, float* __restrict__ out,
    int B, int C, int Hi, int Wi, int BPC) {
    __shared__ float ws_w[32 * 16];
    int Ho = 2 * Hi, Wo = 2 * Wi;
    int co = (blockIdx.x / BPC) % C;
    int b  = blockIdx.x / (BPC * C);
    for (int i = threadIdx.x; i < C * 16; i += TPB) {
        int ci = i >> 4, t = i & 15;
        ws_w[i] = wt[((size_t)ci * C + co) * 16 + t];
    }
    __syncthreads();
    int nq = Wo >> 2;
    int r = (blockIdx.x % BPC) * TPB + threadIdx.x;
    if (r >= Ho * nq) return;
    int q = r % nq, ho = r / nq;
    int wb = q * 4;
    int p = ho & 1;
    int iy0 = (ho + p) / 2 - 1;
    int iy1 = iy0 + 1;
    int ix0 = wb / 2 - 1;
    bool vy0 = (iy0 >= 0) && (iy0 < Hi);
    bool vy1 = (iy1 >= 0) && (iy1 < Hi);
    float bv = bias[co];
    float a0 = bv, a1 = bv, a2 = bv, a3 = bv;
    const float* ipb = in + (size_t)b * C * Hi * Wi;
    for (int ci = 0; ci < C; ++ci) {
        const float* ip = ipb + (size_t)ci * Hi * Wi;
        float u0 = 0, u1 = 0, u2 = 0, u3 = 0, v0 = 0, v1 = 0, v2 = 0, v3 = 0;
        if (vy0) {
            const float* rw = ip + (size_t)iy0 * Wi;
            if (ix0 >= 0) u0 = rw[ix0];
            u1 = rw[ix0 + 1]; u2 = rw[ix0 + 2];
            if (ix0 + 3 < Wi) u3 = rw[ix0 + 3];
        }
        if (vy1) {
            const float* rw = ip + (size_t)iy1 * Wi;
            if (ix0 >= 0) v0 = rw[ix0];
            v1 = rw[ix0 + 1]; v2 = rw[ix0 + 2];
            if (ix0 + 3 < Wi) v3 = rw[ix0 + 3];
        }
        const float* wr0 = ws_w + ci * 16 + (3 - p) * 4;
        const float* wr1 = ws_w + ci * 16 + (1 - p) * 4;
        a0 += u0 * wr0[3] + u1 * wr0[1] + v0 * wr1[3] + v1 * wr1[1];
        a1 += u1 * wr0[2] + u2 * wr0[0] + v1 * wr1[2] + v2 * wr1[0];
        a2 += u1 * wr0[3] + u2 * wr0[1] + v1 * wr1[3] + v2 * wr1[1];
        a3 += u2 * wr0[2] + u3 * wr0[0] + v2 * wr1[2] + v3 * wr1[0];
    }
    size_t o = ((size_t)(b * C + co) * Ho + ho) * Wo + wb;
    *(float4*)(out + o) = make_float4(fmaxf(a0, 0.f), fmaxf(a1, 0.f), fmaxf(a2, 0.f), fmaxf(a3, 0.f));
}

// ---- transpose w_tf3b (co,ci,kd,kh,kw) -> wt[ci][j=kh*3+kw][co][kd] --------
__global__ void transpose_wb_k(const float* __restrict__ wb, float* __restrict__ out) {
    int i = blockIdx.x * TPB + threadIdx.x;
    if (i >= 32 * 9 * 32 * 3) return;
    int kd = i % 3; int t = i / 3;
    int co = t % 32; t /= 32;
    int j  = t % 9;  int ci = t / 9;
    out[i] = wb[(size_t)(co * 32 + ci) * 27 + kd * 9 + j];
}

// ---- transpose w_dc (o,ck) -> wt2[ck][64] ----------------------------------
__global__ void transpose_wdc_k(const float* __restrict__ w, float* __restrict__ out) {
    int i = blockIdx.x * TPB + threadIdx.x;
    if (i >= 63 * 64) return;
    int o = i & 63, ck = i >> 6;
    out[i] = w[o * 63 + ck];
}

// ---- zero the 1-px border of every padded xa plane -------------------------
__global__ void xa_border_k(float* __restrict__ xa_g) {
    int idx = blockIdx.x * TPB + threadIdx.x;
    if (idx >= 448 * 644) return;
    int p = idx / 644, e = idx % 644;
    int off;
    if (e < 162)      off = e;
    else if (e < 324) off = 161 * 162 + (e - 162);
    else if (e < 484) off = (e - 324 + 1) * 162;
    else              off = (e - 484 + 1) * 162 + 161;
    xa_g[(size_t)p * 26244 + off] = 0.f;
}

// ---- conv3d_a: x (B,7,H,W) -> relu -> padded xa [B][32][7][162][162] -------
__global__ __launch_bounds__(TPB) void conv3da_k(
    const float* __restrict__ x, const float* __restrict__ wa,
    const float* __restrict__ ba, float* __restrict__ xa_g,
    int B, int H, int W) {
    __shared__ float w27[27];
    int blk = blockIdx.x;
    int t5 = blk % 25; int rest = blk / 25;
    int d = rest % 7; rest /= 7;
    int co = rest % 32; int b = rest / 32;
    if (threadIdx.x < 27) w27[threadIdx.x] = wa[co * 27 + threadIdx.x];
    __syncthreads();
    int r = t5 * TPB + threadIdx.x;
    if (r >= 160 * 40) return;
    int y = r / 40, x0 = (r % 40) * 4;
    float bv = ba[co];
    float a0 = bv, a1 = bv, a2 = bv, a3 = bv;
#pragma unroll
    for (int kd = 0; kd < 3; ++kd) {
        int dz = d + kd - 1;
        if (dz < 0 || dz >= 7) continue;
        const float* pl = x + ((size_t)(b * 7 + dz)) * H * W;
#pragma unroll
        for (int kh = 0; kh < 3; ++kh) {
            int yy = y + kh - 1;
            if (yy < 0 || yy >= H) continue;
            const float* row = pl + (size_t)yy * W + x0;
            float4 xv = *(const float4*)row;
            float xm = (x0 > 0) ? row[-1] : 0.f;
            float xp = (x0 + 4 < W) ? row[4] : 0.f;
            float w0 = w27[kd * 9 + kh * 3], w1 = w27[kd * 9 + kh * 3 + 1], w2 = w27[kd * 9 + kh * 3 + 2];
            a0 += xm   * w0 + xv.x * w1 + xv.y * w2;
            a1 += xv.x * w0 + xv.y * w1 + xv.z * w2;
            a2 += xv.y * w0 + xv.z * w1 + xv.w * w2;
            a3 += xv.z * w0 + xv.w * w1 + xp   * w2;
        }
    }
    size_t base = ((size_t)((b * 32 + co) * 7 + d)) * 26244 + (size_t)(y + 1) * 162 + (x0 + 1);
    xa_g[base + 0] = fmaxf(a0, 0.f);
    xa_g[base + 1] = fmaxf(a1, 0.f);
    xa_g[base + 2] = fmaxf(a2, 0.f);
    xa_g[base + 3] = fmaxf(a3, 0.f);
}

// ---- conv3d_b + relu + mean, streaming xa from global ----------------------
// grid B*2*400; block 256 = 64 px (8x8) x 4 groups of 4 co (half-split 16 co).
// LDS tile layout [d][row*12][col] -> bank = (12*py+px)%32: uniform 2-way.
__global__ __launch_bounds__(TPB) void conv3db_k(
    const float* __restrict__ xa_g, const float* __restrict__ wt,
    const float* __restrict__ bb, float* __restrict__ out,
    int B, int H, int W) {
    __shared__ float xab[2][840];      // 7 * (10 rows * stride 12)
    const int PLANE = 26244, CI_S = 183708, B_S = 5878656;
    const int RS = 12, DS = 120;       // LDS row / depth strides
    int tile = blockIdx.x % 400;
    int half = (blockIdx.x / 400) & 1;
    int b = blockIdx.x / 800;
    int bx = tile % 20, by = tile / 20;
    int h0 = by * 8, w0 = bx * 8;
    int tid = threadIdx.x;
    int p = tid & 63; int px = p & 7; int py = p >> 3;
    int g = tid >> 6;                     // 0..3 -> co = half*16 + g*4 + r

    int gu = __builtin_amdgcn_readfirstlane(g);
    const float* wbase = wt + half * 48 + gu * 12;

    // hoisted staging offsets: global src + LDS dst (layout-mapped)
    int it0 = tid, it1 = tid + 256, it2 = tid + 512;
    bool h2 = (it2 < 700);
    int dd0 = it0 / 100, rm0 = it0 % 100;
    int xo0 = dd0 * PLANE + (h0 + rm0 / 10) * 162 + (w0 + rm0 % 10);
    int lo0 = dd0 * DS + (rm0 / 10) * RS + rm0 % 10;
    int dd1 = it1 / 100, rm1 = it1 % 100;
    int xo1 = dd1 * PLANE + (h0 + rm1 / 10) * 162 + (w0 + rm1 % 10);
    int lo1 = dd1 * DS + (rm1 / 10) * RS + rm1 % 10;
    int xo2 = 0, lo2 = 0;
    if (h2) {
        int dd2 = it2 / 100, rm2 = it2 % 100;
        xo2 = dd2 * PLANE + (h0 + rm2 / 10) * 162 + (w0 + rm2 % 10);
        lo2 = dd2 * DS + (rm2 / 10) * RS + rm2 % 10;
    }

    const float* xbase = xa_g + (size_t)b * B_S;

    float acc[4][7];
#pragma unroll
    for (int r = 0; r < 4; ++r) {
        float bv = bb[half * 16 + g * 4 + r];
#pragma unroll
        for (int d = 0; d < 7; ++d) acc[r][d] = bv;
    }

    // prologue: ci = 0 tile into buffer 0
    {
        float r0 = xbase[xo0], r1 = xbase[xo1], r2 = h2 ? xbase[xo2] : 0.f;
        xab[0][lo0] = r0; xab[0][lo1] = r1; if (h2) xab[0][lo2] = r2;
    }
    __syncthreads();

    for (int ci = 0; ci < 32; ++ci) {
        int cur = ci & 1, nxt = cur ^ 1;
        bool more = (ci + 1 < 32);
        float r0 = 0.f, r1 = 0.f, r2 = 0.f;
        if (more) {   // issue next-ci tile loads early; latency hides under FMAs
            const float* xs = xbase + (size_t)(ci + 1) * CI_S;
            r0 = xs[xo0]; r1 = xs[xo1]; r2 = h2 ? xs[xo2] : 0.f;
        }
        const float* xab_c = xab[cur];
        const float* wci = wbase + (size_t)ci * 864;   // uniform -> s_load path
#pragma unroll
        for (int kh = 0; kh < 3; ++kh) {
#pragma unroll
            for (int kw = 0; kw < 3; ++kw) {
                int j = kh * 3 + kw;
                float xav[7];
                const float* xb = xab_c + (py + kh) * RS + (px + kw);
#pragma unroll
                for (int d = 0; d < 7; ++d) xav[d] = xb[d * DS];
                const float4* wp = (const float4*)(wci + j * 96);
                float4 w0 = wp[0], w1 = wp[1], w2 = wp[2];
                float wr[4][3] = {{w0.x, w0.y, w0.z}, {w0.w, w1.x, w1.y},
                                  {w1.z, w1.w, w2.x}, {w2.y, w2.z, w2.w}};
#pragma unroll
                for (int r = 0; r < 4; ++r) {
#pragma unroll
                    for (int d = 1; d < 7; ++d) acc[r][d] += xav[d - 1] * wr[r][0];
#pragma unroll
                    for (int d = 0; d < 7; ++d) acc[r][d] += xav[d] * wr[r][1];
#pragma unroll
                    for (int d = 0; d < 6; ++d) acc[r][d] += xav[d + 1] * wr[r][2];
                }
            }
        }
        if (more) {
            xab[nxt][lo0] = r0; xab[nxt][lo1] = r1; if (h2) xab[nxt][lo2] = r2;
        }
        __syncthreads();
    }

    size_t HW = (size_t)H * W;
#pragma unroll
    for (int r = 0; r < 4; ++r) {
        float s = 0.f;
#pragma unroll
        for (int d = 0; d < 7; ++d) s += fmaxf(acc[r][d], 0.f);
        int co = half * 16 + g * 4 + r;
        out[((size_t)(b * 32 + co)) * HW + (size_t)(h0 + py) * W + (w0 + px)] = s * (1.f / 7.f);
    }
}

// ------------- modulated deformable conv, 16 co/thread, scalar weights ------
// wt2: [ck][64] transposed w_dc. Weight reads are wave-uniform -> s_load.
__global__ __launch_bounds__(TPB) void deform_conv_k(
    const float* __restrict__ x, const float* __restrict__ om,
    const float* __restrict__ wt2, const float* __restrict__ bias,
    float* __restrict__ out, int B, int H, int W) {
    int ob = blockIdx.y * 16;
    int idx = blockIdx.x * blockDim.x + threadIdx.x;
    int total = B * H * W;
    if (idx >= total) return;
    int wq = idx % W; int t = idx / W;
    int hq = t % H;   int b = t / H;
    float acc[16];
#pragma unroll
    for (int o = 0; o < 16; ++o) acc[o] = 0.f;
    const size_t HW = (size_t)H * W;
    const float* omb = om + (size_t)b * 189 * HW;
    size_t hw = (size_t)hq * W + wq;
    for (int c = 0; c < 7; ++c) {
        const float* xc = x + ((size_t)(b * 7 + c)) * HW;
#pragma unroll
        for (int k = 0; k < 9; ++k) {
            float dy = omb[(size_t)(c * 18 + k * 2 + 0) * HW + hw];
            float dx = omb[(size_t)(c * 18 + k * 2 + 1) * HW + hw];
            float mv = omb[(size_t)(126 + c * 9 + k) * HW + hw];
            float m = 1.f / (1.f + __expf(-mv));
            float py = (float)hq + (float)(k / 3 - 1) + dy;
            float px = (float)wq + (float)(k % 3 - 1) + dx;
            float y0f = floorf(py), x0f = floorf(px);
            int y0 = (int)y0f, x0 = (int)x0f;
            float wy1 = py - y0f, wx1 = px - x0f;
            float wy0 = 1.f - wy1, wx0 = 1.f - wx1;
            float v00 = 0.f, v01 = 0.f, v10 = 0.f, v11 = 0.f;
            bool yin0 = (y0 >= 0) & (y0 < H);
            bool yin1 = (y0 + 1 >= 0) & (y0 + 1 < H);
            bool xin0 = (x0 >= 0) & (x0 < W);
            bool xin1 = (x0 + 1 >= 0) & (x0 + 1 < W);
            if (yin0) {
                const float* rr = xc + (size_t)y0 * W;
                if (xin0) v00 = rr[x0];
                if (xin1) v01 = rr[x0 + 1];
            }
            if (yin1) {
                const float* rr = xc + (size_t)(y0 + 1) * W;
                if (xin0) v10 = rr[x0];
                if (xin1) v11 = rr[x0 + 1];
            }
            float s = (wy0 * wx0 * v00 + wy0 * wx1 * v01 + wy1 * wx0 * v10 + wy1 * wx1 * v11) * m;
            const float* sw = wt2 + (c * 9 + k) * 64 + ob;   // uniform -> s_load
#pragma unroll
            for (int o = 0; o < 16; ++o) acc[o] += s * sw[o];
        }
    }
    size_t obase = (size_t)b * 64 * HW + hw;
#pragma unroll
    for (int o = 0; o < 16; ++o)
        out[obase + (size_t)(ob + o) * HW] = fmaxf(acc[o] + bias[ob + o], 0.f);
}

extern "C" void kernel_launch(void* const* d_in, const int* in_sizes, int n_in,
                              void* d_out, int out_size, void* d_ws, size_t ws_size,
                              hipStream_t stream) {
    (void)in_sizes; (void)n_in; (void)out_size; (void)ws_size;
    const float* inputs = (const float*)d_in[0];
    const float* w_in   = (const float*)d_in[1];  const float* b_in   = (const float*)d_in[2];
    const float* w_dn1a = (const float*)d_in[3];  const float* b_dn1a = (const float*)d_in[4];
    const float* w_dn1b = (const float*)d_in[5];  const float* b_dn1b = (const float*)d_in[6];
    const float* w_up1a = (const float*)d_in[7];  const float* b_up1a = (const float*)d_in[8];
    const float* wt_up1 = (const float*)d_in[9];  const float* bt_up1 = (const float*)d_in[10];
    const float* w_dn2a = (const float*)d_in[11]; const float* b_dn2a = (const float*)d_in[12];
    const float* w_dn2b = (const float*)d_in[13]; const float* b_dn2b = (const float*)d_in[14];
    const float* w_up2a = (const float*)d_in[15]; const float* b_up2a = (const float*)d_in[16];
    const float* wt_up2 = (const float*)d_in[17]; const float* bt_up2 = (const float*)d_in[18];
    const float* w_tra  = (const float*)d_in[19]; const float* b_tra  = (const float*)d_in[20];
    const float* w_trb  = (const float*)d_in[21]; const float* b_trb  = (const float*)d_in[22];
    const float* wt_tr  = (const float*)d_in[23]; const float* bt_tr  = (const float*)d_in[24];
    const float* w_out  = (const float*)d_in[25]; const float* b_out  = (const float*)d_in[26];
    const float* w_tf3a = (const float*)d_in[27]; const float* b_tf3a = (const float*)d_in[28];
    const float* w_tf3b = (const float*)d_in[29]; const float* b_tf3b = (const float*)d_in[30];
    const float* w_tf2  = (const float*)d_in[31]; const float* b_tf2  = (const float*)d_in[32];
    const float* w_om   = (const float*)d_in[33]; const float* b_om   = (const float*)d_in[34];
    const float* w_dc   = (const float*)d_in[35]; const float* b_dc   = (const float*)d_in[36];
    float* out = (float*)d_out;

    const int B = 2, nf = 32, H = 160, W = 160;
    const size_t n160 = (size_t)B * nf * 160 * 160;
    const size_t n80  = (size_t)B * nf * 80 * 80;
    const size_t n40  = (size_t)B * nf * 40 * 40;
    const size_t n20  = (size_t)B * nf * 20 * 20;

    float* ws = (float*)d_ws;
    float* F0    = ws;                 // also MEAN, later OUTC
    float* TMP80 = F0 + n160;
    float* F1    = TMP80 + n80;
    float* TMP40 = F1 + n80;
    float* F2    = TMP40 + n40;
    float* T20A  = F2 + n40;
    float* T20B  = T20A + n20;
    float* T40   = T20B + n20;
    float* T40B  = T40 + n40;
    float* T80   = T40B + n40;
    float* T80B  = T80 + n80;
    float* T160  = T80B + n80;         // U-Net output t
    float* TF    = T160 + n160;        // FUSED
    float* XA    = TF + n160;          // padded conv_a out: 11,757,312 floats
    float* OM    = XA;                 // ALIAS: OM written after XA is dead
    float* WT    = XA + (size_t)2 * 32 * 7 * 162 * 162;  // 27,648 floats
    float* WT2   = WT + 32 * 9 * 32 * 3;                 // 4,032 floats

    const int bpc160 = bpc_of(160, 40);   // 25
    const int bpc80  = bpc_of(80, 20);    // 7
    const int bpc40  = bpc_of(40, 10);    // 2
    const int bpc20  = bpc_of(20, 5);     // 1

    // prep: weight transposes, border zero, conv_a -> XA
    transpose_wb_k<<<nblk(32 * 9 * 32 * 3), TPB, 0, stream>>>(w_tf3b, WT);
    transpose_wdc_k<<<nblk(63 * 64), TPB, 0, stream>>>(w_dc, WT2);
    xa_border_k<<<nblk(448 * 644), TPB, 0, stream>>>(XA);
    conv3da_k<<<B * 32 * 7 * 25, TPB, 0, stream>>>(inputs, w_tf3a, b_tf3a, XA, B, H, W);

    // --- 2D U-Net branch ---
    conv2d_c4_k<1, 0><<<B * 8 * bpc160, TPB, 0, stream>>>(inputs, w_in, b_in, nullptr, F0, B, 7, 160, 160, nf, 8, bpc160);
    conv2d_s2_t4_k<<<B * nf * bpc80, TPB, 0, stream>>>(F0, w_dn1a, b_dn1a, TMP80, B, nf, 160, 160, nf, bpc80);
    conv2d_t4_k<1, 0><<<B * nf * bpc80, TPB, 0, stream>>>(TMP80, w_dn1b, b_dn1b, nullptr, F1, B, nf, 80, 80, nf, bpc80);
    conv2d_s2_t4_k<<<B * nf * bpc40, TPB, 0, stream>>>(F1, w_dn2a, b_dn2a, TMP40, B, nf, 80, 80, nf, bpc40);
    conv2d_t4_k<1, 0><<<B * nf * bpc40, TPB, 0, stream>>>(TMP40, w_dn2b, b_dn2b, nullptr, F2, B, nf, 40, 40, nf, bpc40);
    conv2d_s2_t4_k<<<B * nf * bpc20, TPB, 0, stream>>>(F2, w_tra, b_tra, T20A, B, nf, 40, 40, nf, bpc20);
    conv2d_t4_k<1, 0><<<B * nf * bpc20, TPB, 0, stream>>>(T20A, w_trb, b_trb, nullptr, T20B, B, nf, 20, 20, nf, bpc20);
    convt2d_t4_k<<<B * nf * bpc40, TPB, 0, stream>>>(T20B, wt_tr, bt_tr, T40, B, nf, 20, 20, bpc40);
    conv2d_cat_t4_k<<<B * nf * bpc40, TPB, 0, stream>>>(T40, F2, w_up2a, b_up2a, T40B, B, nf, nf, 40, 40, nf, bpc40);
    convt2d_t4_k<<<B * nf * bpc80, TPB, 0, stream>>>(T40B, wt_up2, bt_up2, T80, B, nf, 40, 40, bpc80);
    conv2d_cat_t4_k<<<B * nf * bpc80, TPB, 0, stream>>>(T80, F1, w_up1a, b_up1a, T80B, B, nf, nf, 80, 80, nf, bpc80);
    convt2d_t4_k<<<B * nf * bpc160, TPB, 0, stream>>>(T80B, wt_up1, bt_up1, T160, B, nf, 80, 80, bpc160);

    // --- conv3d_b + relu + mean (streaming) -> F0 ---
    conv3db_k<<<B * 2 * 400, TPB, 0, stream>>>(XA, WT, b_tf3b, F0, B, H, W);
    // FUSED = relu(conv_tf2(MEAN) + T160)
    conv2d_c4_k<1, 1><<<B * 8 * bpc160, TPB, 0, stream>>>(F0, w_tf2, b_tf2, T160, TF, B, nf, 160, 160, nf, 8, bpc160);

    // --- offset/mask head (OM overwrites XA region; XA dead by now) ---
    conv2d_c4_k<1, 0><<<B * 8 * bpc160, TPB, 0, stream>>>(TF, w_out, b_out, nullptr, F0, B, nf, 160, 160, nf, 8, bpc160);
    conv2d_c8_k<0><<<B * 24 * bpc160, TPB, 0, stream>>>(F0, w_om, b_om, OM, B, nf, 160, 160, 189, 24, bpc160);

    // --- deformable conv ---
    dim3 dgrid(nblk((long long)B * H * W), 4);
    deform_conv_k<<<dgrid, TPB, 0, stream>>>(inputs, OM, WT2, b_dc, out, B, H, W);
}

// Round 11
// 1034.215 us; speedup vs baseline: 1.0187x; 1.0187x over previous
//
#include <hip/hip_runtime.h>
#include <math.h>

// ---------------------------------------------------------------------------
// STDF forward, round 11: block-size right-sizing for small spatial levels
// (TB=64 @20/40, TB=128 @80 -> 2-4x more blocks, full lanes), merged prep
// kernel. conv3db/deform/c4/c8/160-level kernels identical to round 10.
// ---------------------------------------------------------------------------

#define TPB 256

static inline int nblk(long long total) { return (int)((total + TPB - 1) / TPB); }

// ---------------- 3x3 conv2d, stride 1, 4 outputs/thread, block-uniform co --
template <int TB, int RELU, int HAS_RES>
__global__ __launch_bounds__(TB) void conv2d_t4_k(
    const float* __restrict__ in, const float* __restrict__ w,
    const float* __restrict__ bias, const float* __restrict__ res,
    float* __restrict__ out, int B, int Ci, int H, int W, int Co, int BPC) {
    __shared__ float ws_w[32 * 9];
    int co = (blockIdx.x / BPC) % Co;
    int b  = blockIdx.x / (BPC * Co);
    for (int i = threadIdx.x; i < Ci * 9; i += TB)
        ws_w[i] = w[(size_t)co * Ci * 9 + i];
    __syncthreads();
    int nq = W >> 2;
    int r = (blockIdx.x % BPC) * TB + threadIdx.x;
    if (r >= H * nq) return;
    int q = r % nq, ho = r / nq;
    int wb = q * 4;
    float bv = bias[co];
    float a0 = bv, a1 = bv, a2 = bv, a3 = bv;
    const float* ipb = in + (size_t)b * Ci * H * W;
    for (int ci = 0; ci < Ci; ++ci) {
        const float* ip = ipb + (size_t)ci * H * W;
        const float* wc = ws_w + ci * 9;
#pragma unroll
        for (int kh = 0; kh < 3; ++kh) {
            int y = ho - 1 + kh;
            if (y < 0 || y >= H) continue;
            const float* row = ip + (size_t)y * W + wb;
            float4 xv = *(const float4*)row;
            float xm = (wb > 0) ? row[-1] : 0.f;
            float xp = (wb + 4 < W) ? row[4] : 0.f;
            float w0 = wc[kh * 3], w1 = wc[kh * 3 + 1], w2 = wc[kh * 3 + 2];
            a0 += xm   * w0 + xv.x * w1 + xv.y * w2;
            a1 += xv.x * w0 + xv.y * w1 + xv.z * w2;
            a2 += xv.y * w0 + xv.z * w1 + xv.w * w2;
            a3 += xv.z * w0 + xv.w * w1 + xp   * w2;
        }
    }
    size_t o = ((size_t)(b * Co + co) * H + ho) * W + wb;
    if (HAS_RES) {
        float4 rv = *(const float4*)(res + o);
        a0 += rv.x; a1 += rv.y; a2 += rv.z; a3 += rv.w;
    }
    if (RELU) { a0 = fmaxf(a0, 0.f); a1 = fmaxf(a1, 0.f); a2 = fmaxf(a2, 0.f); a3 = fmaxf(a3, 0.f); }
    *(float4*)(out + o) = make_float4(a0, a1, a2, a3);
}

// ------- 3x3 conv2d, stride 1, 4 outputs x 4 co per thread -----------------
template <int RELU, int HAS_RES>
__global__ __launch_bounds__(TPB) void conv2d_c4_k(
    const float* __restrict__ in, const float* __restrict__ w,
    const float* __restrict__ bias, const float* __restrict__ res,
    float* __restrict__ out, int B, int Ci, int H, int W, int Co, int COG, int BPC) {
    __shared__ float ws_w[4 * 32 * 9];
    int cog = (blockIdx.x / BPC) % COG;
    int b   = blockIdx.x / (BPC * COG);
    int co0 = cog * 4;
    int nw = Ci * 9;
    for (int i = threadIdx.x; i < 4 * nw; i += TPB) {
        int cr = i / nw; int co = co0 + cr;
        ws_w[i] = (co < Co) ? w[(size_t)co * nw + (i - cr * nw)] : 0.f;
    }
    __syncthreads();
    int nq = W >> 2;
    int r = (blockIdx.x % BPC) * TPB + threadIdx.x;
    if (r >= H * nq) return;
    int q = r % nq, ho = r / nq;
    int wb = q * 4;
    float a[4][4];
#pragma unroll
    for (int cr = 0; cr < 4; ++cr) {
        float bv = (co0 + cr < Co) ? bias[co0 + cr] : 0.f;
        a[cr][0] = bv; a[cr][1] = bv; a[cr][2] = bv; a[cr][3] = bv;
    }
    const float* ipb = in + (size_t)b * Ci * H * W;
    for (int ci = 0; ci < Ci; ++ci) {
        const float* ip = ipb + (size_t)ci * H * W;
#pragma unroll
        for (int kh = 0; kh < 3; ++kh) {
            int y = ho - 1 + kh;
            if (y < 0 || y >= H) continue;
            const float* row = ip + (size_t)y * W + wb;
            float4 xv = *(const float4*)row;
            float x_[6];
            x_[0] = (wb > 0) ? row[-1] : 0.f;
            x_[1] = xv.x; x_[2] = xv.y; x_[3] = xv.z; x_[4] = xv.w;
            x_[5] = (wb + 4 < W) ? row[4] : 0.f;
#pragma unroll
            for (int cr = 0; cr < 4; ++cr) {
                const float* wc = ws_w + cr * nw + ci * 9 + kh * 3;
                float w0 = wc[0], w1 = wc[1], w2 = wc[2];
                a[cr][0] += x_[0] * w0 + x_[1] * w1 + x_[2] * w2;
                a[cr][1] += x_[1] * w0 + x_[2] * w1 + x_[3] * w2;
                a[cr][2] += x_[2] * w0 + x_[3] * w1 + x_[4] * w2;
                a[cr][3] += x_[3] * w0 + x_[4] * w1 + x_[5] * w2;
            }
        }
    }
#pragma unroll
    for (int cr = 0; cr < 4; ++cr) {
        int co = co0 + cr;
        if (co >= Co) break;
        size_t o = ((size_t)(b * Co + co) * H + ho) * W + wb;
        float a0 = a[cr][0], a1 = a[cr][1], a2 = a[cr][2], a3 = a[cr][3];
        if (HAS_RES) {
            float4 rv = *(const float4*)(res + o);
            a0 += rv.x; a1 += rv.y; a2 += rv.z; a3 += rv.w;
        }
        if (RELU) { a0 = fmaxf(a0, 0.f); a1 = fmaxf(a1, 0.f); a2 = fmaxf(a2, 0.f); a3 = fmaxf(a3, 0.f); }
        *(float4*)(out + o) = make_float4(a0, a1, a2, a3);
    }
}

// ------- 3x3 conv2d, stride 1, 4 outputs x 8 co per thread (for w_om) ------
template <int RELU>
__global__ __launch_bounds__(TPB) void conv2d_c8_k(
    const float* __restrict__ in, const float* __restrict__ w,
    const float* __restrict__ bias, float* __restrict__ out,
    int B, int Ci, int H, int W, int Co, int COG, int BPC) {
    __shared__ __align__(16) float4 wsa[32 * 9];
    __shared__ __align__(16) float4 wsb[32 * 9];
    int cog = (blockIdx.x / BPC) % COG;
    int b   = blockIdx.x / (BPC * COG);
    int co0 = cog * 8;
    int nw = Ci * 9;
    for (int i = threadIdx.x; i < nw; i += TPB) {
        float4 v, u;
        v.x = (co0 + 0 < Co) ? w[(size_t)(co0 + 0) * nw + i] : 0.f;
        v.y = (co0 + 1 < Co) ? w[(size_t)(co0 + 1) * nw + i] : 0.f;
        v.z = (co0 + 2 < Co) ? w[(size_t)(co0 + 2) * nw + i] : 0.f;
        v.w = (co0 + 3 < Co) ? w[(size_t)(co0 + 3) * nw + i] : 0.f;
        u.x = (co0 + 4 < Co) ? w[(size_t)(co0 + 4) * nw + i] : 0.f;
        u.y = (co0 + 5 < Co) ? w[(size_t)(co0 + 5) * nw + i] : 0.f;
        u.z = (co0 + 6 < Co) ? w[(size_t)(co0 + 6) * nw + i] : 0.f;
        u.w = (co0 + 7 < Co) ? w[(size_t)(co0 + 7) * nw + i] : 0.f;
        wsa[i] = v; wsb[i] = u;
    }
    __syncthreads();
    int nq = W >> 2;
    int r = (blockIdx.x % BPC) * TPB + threadIdx.x;
    if (r >= H * nq) return;
    int q = r % nq, ho = r / nq;
    int wb = q * 4;
    float a[8][4];
#pragma unroll
    for (int cr = 0; cr < 8; ++cr) {
        float bv = (co0 + cr < Co) ? bias[co0 + cr] : 0.f;
        a[cr][0] = bv; a[cr][1] = bv; a[cr][2] = bv; a[cr][3] = bv;
    }
    const float* ipb = in + (size_t)b * Ci * H * W;
    for (int ci = 0; ci < Ci; ++ci) {
        const float* ip = ipb + (size_t)ci * H * W;
#pragma unroll
        for (int kh = 0; kh < 3; ++kh) {
            int y = ho - 1 + kh;
            if (y < 0 || y >= H) continue;
            const float* row = ip + (size_t)y * W + wb;
            float4 xv = *(const float4*)row;
            float x_[6];
            x_[0] = (wb > 0) ? row[-1] : 0.f;
            x_[1] = xv.x; x_[2] = xv.y; x_[3] = xv.z; x_[4] = xv.w;
            x_[5] = (wb + 4 < W) ? row[4] : 0.f;
#pragma unroll
            for (int kw = 0; kw < 3; ++kw) {
                float4 wv = wsa[ci * 9 + kh * 3 + kw];
                float4 wu = wsb[ci * 9 + kh * 3 + kw];
                float x0 = x_[kw], x1 = x_[kw + 1], x2 = x_[kw + 2], x3 = x_[kw + 3];
                a[0][0] += x0 * wv.x; a[0][1] += x1 * wv.x; a[0][2] += x2 * wv.x; a[0][3] += x3 * wv.x;
                a[1][0] += x0 * wv.y; a[1][1] += x1 * wv.y; a[1][2] += x2 * wv.y; a[1][3] += x3 * wv.y;
                a[2][0] += x0 * wv.z; a[2][1] += x1 * wv.z; a[2][2] += x2 * wv.z; a[2][3] += x3 * wv.z;
                a[3][0] += x0 * wv.w; a[3][1] += x1 * wv.w; a[3][2] += x2 * wv.w; a[3][3] += x3 * wv.w;
                a[4][0] += x0 * wu.x; a[4][1] += x1 * wu.x; a[4][2] += x2 * wu.x; a[4][3] += x3 * wu.x;
                a[5][0] += x0 * wu.y; a[5][1] += x1 * wu.y; a[5][2] += x2 * wu.y; a[5][3] += x3 * wu.y;
                a[6][0] += x0 * wu.z; a[6][1] += x1 * wu.z; a[6][2] += x2 * wu.z; a[6][3] += x3 * wu.z;
                a[7][0] += x0 * wu.w; a[7][1] += x1 * wu.w; a[7][2] += x2 * wu.w; a[7][3] += x3 * wu.w;
            }
        }
    }
#pragma unroll
    for (int cr = 0; cr < 8; ++cr) {
        int co = co0 + cr;
        if (co >= Co) break;
        size_t o = ((size_t)(b * Co + co) * H + ho) * W + wb;
        float a0 = a[cr][0], a1 = a[cr][1], a2 = a[cr][2], a3 = a[cr][3];
        if (RELU) { a0 = fmaxf(a0, 0.f); a1 = fmaxf(a1, 0.f); a2 = fmaxf(a2, 0.f); a3 = fmaxf(a3, 0.f); }
        *(float4*)(out + o) = make_float4(a0, a1, a2, a3);
    }
}

// ------------- 3x3 conv2d over concat of two 32-ch inputs, stride 1, relu ---
template <int TB>
__global__ __launch_bounds__(TB) void conv2d_cat_t4_k(
    const float* __restrict__ in1, const float* __restrict__ in2,
    const float* __restrict__ w, const float* __restrict__ bias,
    float* __restrict__ out, int B, int C1, int C2, int H, int W, int Co, int BPC) {
    __shared__ float ws_w[64 * 9];
    int Ci = C1 + C2;
    int co = (blockIdx.x / BPC) % Co;
    int b  = blockIdx.x / (BPC * Co);
    for (int i = threadIdx.x; i < Ci * 9; i += TB)
        ws_w[i] = w[(size_t)co * Ci * 9 + i];
    __syncthreads();
    int nq = W >> 2;
    int r = (blockIdx.x % BPC) * TB + threadIdx.x;
    if (r >= H * nq) return;
    int q = r % nq, ho = r / nq;
    int wb = q * 4;
    float bv = bias[co];
    float a0 = bv, a1 = bv, a2 = bv, a3 = bv;
    for (int ci = 0; ci < Ci; ++ci) {
        const float* ip = (ci < C1)
            ? in1 + ((size_t)(b * C1 + ci)) * H * W
            : in2 + ((size_t)(b * C2 + (ci - C1))) * H * W;
        const float* wc = ws_w + ci * 9;
#pragma unroll
        for (int kh = 0; kh < 3; ++kh) {
            int y = ho - 1 + kh;
            if (y < 0 || y >= H) continue;
            const float* row = ip + (size_t)y * W + wb;
            float4 xv = *(const float4*)row;
            float xm = (wb > 0) ? row[-1] : 0.f;
            float xp = (wb + 4 < W) ? row[4] : 0.f;
            float w0 = wc[kh * 3], w1 = wc[kh * 3 + 1], w2 = wc[kh * 3 + 2];
            a0 += xm   * w0 + xv.x * w1 + xv.y * w2;
            a1 += xv.x * w0 + xv.y * w1 + xv.z * w2;
            a2 += xv.y * w0 + xv.z * w1 + xv.w * w2;
            a3 += xv.z * w0 + xv.w * w1 + xp   * w2;
        }
    }
    size_t o = ((size_t)(b * Co + co) * H + ho) * W + wb;
    *(float4*)(out + o) = make_float4(fmaxf(a0, 0.f), fmaxf(a1, 0.f), fmaxf(a2, 0.f), fmaxf(a3, 0.f));
}

// ------------- 3x3 conv2d, stride 2, 4 outputs/thread, relu ----------------
template <int TB>
__global__ __launch_bounds__(TB) void conv2d_s2_t4_k(
    const float* __restrict__ in, const float* __restrict__ w,
    const float* __restrict__ bias, float* __restrict__ out,
    int B, int Ci, int Hi, int Wi, int Co, int BPC) {
    __shared__ float ws_w[32 * 9];
    int Ho = Hi >> 1, Wo = Wi >> 1;
    int co = (blockIdx.x / BPC) % Co;
    int b  = blockIdx.x / (BPC * Co);
    for (int i = threadIdx.x; i < Ci * 9; i += TB)
        ws_w[i] = w[(size_t)co * Ci * 9 + i];
    __syncthreads();
    int nq = Wo >> 2;
    int r = (blockIdx.x % BPC) * TB + threadIdx.x;
    if (r >= Ho * nq) return;
    int q = r % nq, ho = r / nq;
    int wb = q * 4;
    float bv = bias[co];
    float a0 = bv, a1 = bv, a2 = bv, a3 = bv;
    const float* ipb = in + (size_t)b * Ci * Hi * Wi;
    for (int ci = 0; ci < Ci; ++ci) {
        const float* ip = ipb + (size_t)ci * Hi * Wi;
        const float* wc = ws_w + ci * 9;
#pragma unroll
        for (int kh = 0; kh < 3; ++kh) {
            int y = 2 * ho - 1 + kh;
            if (y < 0 || y >= Hi) continue;
            const float* row = ip + (size_t)y * Wi;
            float z0 = (2 * wb - 1 >= 0) ? row[2 * wb - 1] : 0.f;
            float4 za = *(const float4*)(row + 2 * wb);
            float4 zb = *(const float4*)(row + 2 * wb + 4);
            float w0 = wc[kh * 3], w1 = wc[kh * 3 + 1], w2 = wc[kh * 3 + 2];
            a0 += z0   * w0 + za.x * w1 + za.y * w2;
            a1 += za.y * w0 + za.z * w1 + za.w * w2;
            a2 += za.w * w0 + zb.x * w1 + zb.y * w2;
            a3 += zb.y * w0 + zb.z * w1 + zb.w * w2;
        }
    }
    size_t o = ((size_t)(b * Co + co) * Ho + ho) * Wo + wb;
    *(float4*)(out + o) = make_float4(fmaxf(a0, 0.f), fmaxf(a1, 0.f), fmaxf(a2, 0.f), fmaxf(a3, 0.f));
}

// ------------- transposed conv 4x4 stride 2, 4 outputs/thread, relu --------
template <int TB>
__global__ __launch_bounds__(TB) void convt2d_t4_k(
    const float* __restrict__ in, const float* __restrict__ wt,
    const float* __restrict__ bias, float* __restrict__ out,
    int B, int C, int Hi, int Wi, int BPC) {
    __shared__ float ws_w[32 * 16];
    int Ho = 2 * Hi, Wo = 2 * Wi;
    int co = (blockIdx.x / BPC) % C;
    int b  = blockIdx.x / (BPC * C);
    for (int i = threadIdx.x; i < C * 16; i += TB) {
        int ci = i >> 4, t = i & 15;
        ws_w[i] = wt[((size_t)ci * C + co) * 16 + t];
    }
    __syncthreads();
    int nq = Wo >> 2;
    int r = (blockIdx.x % BPC) * TB + threadIdx.x;
    if (r >= Ho * nq) return;
    int q = r % nq, ho = r / nq;
    int wb = q * 4;
    int p = ho & 1;
    int iy0 = (ho + p) / 2 - 1;
    int iy1 = iy0 + 1;
    int ix0 = wb / 2 - 1;
    bool vy0 = (iy0 >= 0) && (iy0 < Hi);
    bool vy1 = (iy1 >= 0) && (iy1 < Hi);
    float bv = bias[co];
    float a0 = bv, a1 = bv, a2 = bv, a3 = bv;
    const float* ipb = in + (size_t)b * C * Hi * Wi;
    for (int ci = 0; ci < C; ++ci) {
        const float* ip = ipb + (size_t)ci * Hi * Wi;
        float u0 = 0, u1 = 0, u2 = 0, u3 = 0, v0 = 0, v1 = 0, v2 = 0, v3 = 0;
        if (vy0) {
            const float* rw = ip + (size_t)iy0 * Wi;
            if (ix0 >= 0) u0 = rw[ix0];
            u1 = rw[ix0 + 1]; u2 = rw[ix0 + 2];
            if (ix0 + 3 < Wi) u3 = rw[ix0 + 3];
        }
        if (vy1) {
            const float* rw = ip + (size_t)iy1 * Wi;
            if (ix0 >= 0) v0 = rw[ix0];
            v1 = rw[ix0 + 1]; v2 = rw[ix0 + 2];
            if (ix0 + 3 < Wi) v3 = rw[ix0 + 3];
        }
        const float* wr0 = ws_w + ci * 16 + (3 - p) * 4;
        const float* wr1 = ws_w + ci * 16 + (1 - p) * 4;
        a0 += u0 * wr0[3] + u1 * wr0[1] + v0 * wr1[3] + v1 * wr1[1];
        a1 += u1 * wr0[2] + u2 * wr0[0] + v1 * wr1[2] + v2 * wr1[0];
        a2 += u1 * wr0[3] + u2 * wr0[1] + v1 * wr1[3] + v2 * wr1[1];
        a3 += u2 * wr0[2] + u3 * wr0[0] + v2 * wr1[2] + v3 * wr1[0];
    }
    size_t o = ((size_t)(b * C + co) * Ho + ho) * Wo + wb;
    *(float4*)(out + o) = make_float4(fmaxf(a0, 0.f), fmaxf(a1, 0.f), fmaxf(a2, 0.f), fmaxf(a3, 0.f));
}

// ---- merged prep: wb transpose + wdc transpose + xa border zero -------------
__global__ void prep_k(const float* __restrict__ wb, const float* __restrict__ wdc,
                       float* __restrict__ wt, float* __restrict__ wt2,
                       float* __restrict__ xa_g) {
    int i = blockIdx.x * TPB + threadIdx.x;
    if (i < 27648) {
        int kd = i % 3; int t = i / 3;
        int co = t % 32; t /= 32;
        int j  = t % 9;  int ci = t / 9;
        wt[i] = wb[(size_t)(co * 32 + ci) * 27 + kd * 9 + j];
        return;
    }
    int i2 = i - 27648;
    if (i2 < 4032) {
        int o = i2 & 63, ck = i2 >> 6;
        wt2[i2] = wdc[o * 63 + ck];
        return;
    }
    int i3 = i2 - 4032;
    if (i3 >= 448 * 644) return;
    int pl = i3 / 644, e = i3 % 644;
    int off;
    if (e < 162)      off = e;
    else if (e < 324) off = 161 * 162 + (e - 162);
    else if (e < 484) off = (e - 324 + 1) * 162;
    else              off = (e - 484 + 1) * 162 + 161;
    xa_g[(size_t)pl * 26244 + off] = 0.f;
}

// ---- conv3d_a: x (B,7,H,W) -> relu -> padded xa [B][32][7][162][162] -------
__global__ __launch_bounds__(TPB) void conv3da_k(
    const float* __restrict__ x, const float* __restrict__ wa,
    const float* __restrict__ ba, float* __restrict__ xa_g,
    int B, int H, int W) {
    __shared__ float w27[27];
    int blk = blockIdx.x;
    int t5 = blk % 25; int rest = blk / 25;
    int d = rest % 7; rest /= 7;
    int co = rest % 32; int b = rest / 32;
    if (threadIdx.x < 27) w27[threadIdx.x] = wa[co * 27 + threadIdx.x];
    __syncthreads();
    int r = t5 * TPB + threadIdx.x;
    if (r >= 160 * 40) return;
    int y = r / 40, x0 = (r % 40) * 4;
    float bv = ba[co];
    float a0 = bv, a1 = bv, a2 = bv, a3 = bv;
#pragma unroll
    for (int kd = 0; kd < 3; ++kd) {
        int dz = d + kd - 1;
        if (dz < 0 || dz >= 7) continue;
        const float* pl = x + ((size_t)(b * 7 + dz)) * H * W;
#pragma unroll
        for (int kh = 0; kh < 3; ++kh) {
            int yy = y + kh - 1;
            if (yy < 0 || yy >= H) continue;
            const float* row = pl + (size_t)yy * W + x0;
            float4 xv = *(const float4*)row;
            float xm = (x0 > 0) ? row[-1] : 0.f;
            float xp = (x0 + 4 < W) ? row[4] : 0.f;
            float w0 = w27[kd * 9 + kh * 3], w1 = w27[kd * 9 + kh * 3 + 1], w2 = w27[kd * 9 + kh * 3 + 2];
            a0 += xm   * w0 + xv.x * w1 + xv.y * w2;
            a1 += xv.x * w0 + xv.y * w1 + xv.z * w2;
            a2 += xv.y * w0 + xv.z * w1 + xv.w * w2;
            a3 += xv.z * w0 + xv.w * w1 + xp   * w2;
        }
    }
    size_t base = ((size_t)((b * 32 + co) * 7 + d)) * 26244 + (size_t)(y + 1) * 162 + (x0 + 1);
    xa_g[base + 0] = fmaxf(a0, 0.f);
    xa_g[base + 1] = fmaxf(a1, 0.f);
    xa_g[base + 2] = fmaxf(a2, 0.f);
    xa_g[base + 3] = fmaxf(a3, 0.f);
}

// ---- conv3d_b + relu + mean, streaming xa from global (round-10 verified) --
__global__ __launch_bounds__(TPB) void conv3db_k(
    const float* __restrict__ xa_g, const float* __restrict__ wt,
    const float* __restrict__ bb, float* __restrict__ out,
    int B, int H, int W) {
    __shared__ float xab[2][840];
    const int PLANE = 26244, CI_S = 183708, B_S = 5878656;
    const int RS = 12, DS = 120;
    int tile = blockIdx.x % 400;
    int half = (blockIdx.x / 400) & 1;
    int b = blockIdx.x / 800;
    int bx = tile % 20, by = tile / 20;
    int h0 = by * 8, w0 = bx * 8;
    int tid = threadIdx.x;
    int p = tid & 63; int px = p & 7; int py = p >> 3;
    int g = tid >> 6;

    int gu = __builtin_amdgcn_readfirstlane(g);
    const float* wbase = wt + half * 48 + gu * 12;

    int it0 = tid, it1 = tid + 256, it2 = tid + 512;
    bool h2 = (it2 < 700);
    int dd0 = it0 / 100, rm0 = it0 % 100;
    int xo0 = dd0 * PLANE + (h0 + rm0 / 10) * 162 + (w0 + rm0 % 10);
    int lo0 = dd0 * DS + (rm0 / 10) * RS + rm0 % 10;
    int dd1 = it1 / 100, rm1 = it1 % 100;
    int xo1 = dd1 * PLANE + (h0 + rm1 / 10) * 162 + (w0 + rm1 % 10);
    int lo1 = dd1 * DS + (rm1 / 10) * RS + rm1 % 10;
    int xo2 = 0, lo2 = 0;
    if (h2) {
        int dd2 = it2 / 100, rm2 = it2 % 100;
        xo2 = dd2 * PLANE + (h0 + rm2 / 10) * 162 + (w0 + rm2 % 10);
        lo2 = dd2 * DS + (rm2 / 10) * RS + rm2 % 10;
    }

    const float* xbase = xa_g + (size_t)b * B_S;

    float acc[4][7];
#pragma unroll
    for (int r = 0; r < 4; ++r) {
        float bv = bb[half * 16 + g * 4 + r];
#pragma unroll
        for (int d = 0; d < 7; ++d) acc[r][d] = bv;
    }

    {
        float r0 = xbase[xo0], r1 = xbase[xo1], r2 = h2 ? xbase[xo2] : 0.f;
        xab[0][lo0] = r0; xab[0][lo1] = r1; if (h2) xab[0][lo2] = r2;
    }
    __syncthreads();

    for (int ci = 0; ci < 32; ++ci) {
        int cur = ci & 1, nxt = cur ^ 1;
        bool more = (ci + 1 < 32);
        float r0 = 0.f, r1 = 0.f, r2 = 0.f;
        if (more) {
            const float* xs = xbase + (size_t)(ci + 1) * CI_S;
            r0 = xs[xo0]; r1 = xs[xo1]; r2 = h2 ? xs[xo2] : 0.f;
        }
        const float* xab_c = xab[cur];
        const float* wci = wbase + (size_t)ci * 864;
#pragma unroll
        for (int kh = 0; kh < 3; ++kh) {
#pragma unroll
            for (int kw = 0; kw < 3; ++kw) {
                int j = kh * 3 + kw;
                float xav[7];
                const float* xb = xab_c + (py + kh) * RS + (px + kw);
#pragma unroll
                for (int d = 0; d < 7; ++d) xav[d] = xb[d * DS];
                const float4* wp = (const float4*)(wci + j * 96);
                float4 w0 = wp[0], w1 = wp[1], w2 = wp[2];
                float wr[4][3] = {{w0.x, w0.y, w0.z}, {w0.w, w1.x, w1.y},
                                  {w1.z, w1.w, w2.x}, {w2.y, w2.z, w2.w}};
#pragma unroll
                for (int r = 0; r < 4; ++r) {
#pragma unroll
                    for (int d = 1; d < 7; ++d) acc[r][d] += xav[d - 1] * wr[r][0];
#pragma unroll
                    for (int d = 0; d < 7; ++d) acc[r][d] += xav[d] * wr[r][1];
#pragma unroll
                    for (int d = 0; d < 6; ++d) acc[r][d] += xav[d + 1] * wr[r][2];
                }
            }
        }
        if (more) {
            xab[nxt][lo0] = r0; xab[nxt][lo1] = r1; if (h2) xab[nxt][lo2] = r2;
        }
        __syncthreads();
    }

    size_t HW = (size_t)H * W;
#pragma unroll
    for (int r = 0; r < 4; ++r) {
        float s = 0.f;
#pragma unroll
        for (int d = 0; d < 7; ++d) s += fmaxf(acc[r][d], 0.f);
        int co = half * 16 + g * 4 + r;
        out[((size_t)(b * 32 + co)) * HW + (size_t)(h0 + py) * W + (w0 + px)] = s * (1.f / 7.f);
    }
}

// ------------- modulated deformable conv, 16 co/thread, scalar weights ------
__global__ __launch_bounds__(TPB) void deform_conv_k(
    const float* __restrict__ x, const float* __restrict__ om,
    const float* __restrict__ wt2, const float* __restrict__ bias,
    float* __restrict__ out, int B, int H, int W) {
    int ob = blockIdx.y * 16;
    int idx = blockIdx.x * blockDim.x + threadIdx.x;
    int total = B * H * W;
    if (idx >= total) return;
    int wq = idx % W; int t = idx / W;
    int hq = t % H;   int b = t / H;
    float acc[16];
#pragma unroll
    for (int o = 0; o < 16; ++o) acc[o] = 0.f;
    const size_t HW = (size_t)H * W;
    const float* omb = om + (size_t)b * 189 * HW;
    size_t hw = (size_t)hq * W + wq;
    for (int c = 0; c < 7; ++c) {
        const float* xc = x + ((size_t)(b * 7 + c)) * HW;
#pragma unroll
        for (int k = 0; k < 9; ++k) {
            float dy = omb[(size_t)(c * 18 + k * 2 + 0) * HW + hw];
            float dx = omb[(size_t)(c * 18 + k * 2 + 1) * HW + hw];
            float mv = omb[(size_t)(126 + c * 9 + k) * HW + hw];
            float m = 1.f / (1.f + __expf(-mv));
            float py = (float)hq + (float)(k / 3 - 1) + dy;
            float px = (float)wq + (float)(k % 3 - 1) + dx;
            float y0f = floorf(py), x0f = floorf(px);
            int y0 = (int)y0f, x0 = (int)x0f;
            float wy1 = py - y0f, wx1 = px - x0f;
            float wy0 = 1.f - wy1, wx0 = 1.f - wx1;
            float v00 = 0.f, v01 = 0.f, v10 = 0.f, v11 = 0.f;
            bool yin0 = (y0 >= 0) & (y0 < H);
            bool yin1 = (y0 + 1 >= 0) & (y0 + 1 < H);
            bool xin0 = (x0 >= 0) & (x0 < W);
            bool xin1 = (x0 + 1 >= 0) & (x0 + 1 < W);
            if (yin0) {
                const float* rr = xc + (size_t)y0 * W;
                if (xin0) v00 = rr[x0];
                if (xin1) v01 = rr[x0 + 1];
            }
            if (yin1) {
                const float* rr = xc + (size_t)(y0 + 1) * W;
                if (xin0) v10 = rr[x0];
                if (xin1) v11 = rr[x0 + 1];
            }
            float s = (wy0 * wx0 * v00 + wy0 * wx1 * v01 + wy1 * wx0 * v10 + wy1 * wx1 * v11) * m;
            const float* sw = wt2 + (c * 9 + k) * 64 + ob;
#pragma unroll
            for (int o = 0; o < 16; ++o) acc[o] += s * sw[o];
        }
    }
    size_t obase = (size_t)b * 64 * HW + hw;
#pragma unroll
    for (int o = 0; o < 16; ++o)
        out[obase + (size_t)(ob + o) * HW] = fmaxf(acc[o] + bias[ob + o], 0.f);
}

extern "C" void kernel_launch(void* const* d_in, const int* in_sizes, int n_in,
                              void* d_out, int out_size, void* d_ws, size_t ws_size,
                              hipStream_t stream) {
    (void)in_sizes; (void)n_in; (void)out_size; (void)ws_size;
    const float* inputs = (const float*)d_in[0];
    const float* w_in   = (const float*)d_in[1];  const float* b_in   = (const float*)d_in[2];
    const float* w_dn1a = (const float*)d_in[3];  const float* b_dn1a = (const float*)d_in[4];
    const float* w_dn1b = (const float*)d_in[5];  const float* b_dn1b = (const float*)d_in[6];
    const float* w_up1a = (const float*)d_in[7];  const float* b_up1a = (const float*)d_in[8];
    const float* wt_up1 = (const float*)d_in[9];  const float* bt_up1 = (const float*)d_in[10];
    const float* w_dn2a = (const float*)d_in[11]; const float* b_dn2a = (const float*)d_in[12];
    const float* w_dn2b = (const float*)d_in[13]; const float* b_dn2b = (const float*)d_in[14];
    const float* w_up2a = (const float*)d_in[15]; const float* b_up2a = (const float*)d_in[16];
    const float* wt_up2 = (const float*)d_in[17]; const float* bt_up2 = (const float*)d_in[18];
    const float* w_tra  = (const float*)d_in[19]; const float* b_tra  = (const float*)d_in[20];
    const float* w_trb  = (const float*)d_in[21]; const float* b_trb  = (const float*)d_in[22];
    const float* wt_tr  = (const float*)d_in[23]; const float* bt_tr  = (const float*)d_in[24];
    const float* w_out  = (const float*)d_in[25]; const float* b_out  = (const float*)d_in[26];
    const float* w_tf3a = (const float*)d_in[27]; const float* b_tf3a = (const float*)d_in[28];
    const float* w_tf3b = (const float*)d_in[29]; const float* b_tf3b = (const float*)d_in[30];
    const float* w_tf2  = (const float*)d_in[31]; const float* b_tf2  = (const float*)d_in[32];
    const float* w_om   = (const float*)d_in[33]; const float* b_om   = (const float*)d_in[34];
    const float* w_dc   = (const float*)d_in[35]; const float* b_dc   = (const float*)d_in[36];
    float* out = (float*)d_out;

    const int B = 2, nf = 32, H = 160, W = 160;
    const size_t n160 = (size_t)B * nf * 160 * 160;
    const size_t n80  = (size_t)B * nf * 80 * 80;
    const size_t n40  = (size_t)B * nf * 40 * 40;
    const size_t n20  = (size_t)B * nf * 20 * 20;

    float* ws = (float*)d_ws;
    float* F0    = ws;
    float* TMP80 = F0 + n160;
    float* F1    = TMP80 + n80;
    float* TMP40 = F1 + n80;
    float* F2    = TMP40 + n40;
    float* T20A  = F2 + n40;
    float* T20B  = T20A + n20;
    float* T40   = T20B + n20;
    float* T40B  = T40 + n40;
    float* T80   = T40B + n40;
    float* T80B  = T80 + n80;
    float* T160  = T80B + n80;
    float* TF    = T160 + n160;
    float* XA    = TF + n160;
    float* OM    = XA;                 // ALIAS: OM written after XA is dead
    float* WT    = XA + (size_t)2 * 32 * 7 * 162 * 162;
    float* WT2   = WT + 32 * 9 * 32 * 3;

    const int bpc160 = 25;            // ceil(160*40/256)
    const int bpc80_128 = 13;         // ceil(80*20/128)
    const int bpc40_64  = 7;          // ceil(40*10/64)
    const int bpc20_64  = 2;          // ceil(20*5/64)

    // prep (merged) + conv_a
    prep_k<<<nblk(27648 + 4032 + 448 * 644), TPB, 0, stream>>>(w_tf3b, w_dc, WT, WT2, XA);
    conv3da_k<<<B * 32 * 7 * 25, TPB, 0, stream>>>(inputs, w_tf3a, b_tf3a, XA, B, H, W);

    // --- 2D U-Net branch ---
    conv2d_c4_k<1, 0><<<B * 8 * bpc160, TPB, 0, stream>>>(inputs, w_in, b_in, nullptr, F0, B, 7, 160, 160, nf, 8, bpc160);
    conv2d_s2_t4_k<128><<<B * nf * bpc80_128, 128, 0, stream>>>(F0, w_dn1a, b_dn1a, TMP80, B, nf, 160, 160, nf, bpc80_128);
    conv2d_t4_k<128, 1, 0><<<B * nf * bpc80_128, 128, 0, stream>>>(TMP80, w_dn1b, b_dn1b, nullptr, F1, B, nf, 80, 80, nf, bpc80_128);
    conv2d_s2_t4_k<64><<<B * nf * bpc40_64, 64, 0, stream>>>(F1, w_dn2a, b_dn2a, TMP40, B, nf, 80, 80, nf, bpc40_64);
    conv2d_t4_k<64, 1, 0><<<B * nf * bpc40_64, 64, 0, stream>>>(TMP40, w_dn2b, b_dn2b, nullptr, F2, B, nf, 40, 40, nf, bpc40_64);
    conv2d_s2_t4_k<64><<<B * nf * bpc20_64, 64, 0, stream>>>(F2, w_tra, b_tra, T20A, B, nf, 40, 40, nf, bpc20_64);
    conv2d_t4_k<64, 1, 0><<<B * nf * bpc20_64, 64, 0, stream>>>(T20A, w_trb, b_trb, nullptr, T20B, B, nf, 20, 20, nf, bpc20_64);
    convt2d_t4_k<64><<<B * nf * bpc40_64, 64, 0, stream>>>(T20B, wt_tr, bt_tr, T40, B, nf, 20, 20, bpc40_64);
    conv2d_cat_t4_k<64><<<B * nf * bpc40_64, 64, 0, stream>>>(T40, F2, w_up2a, b_up2a, T40B, B, nf, nf, 40, 40, nf, bpc40_64);
    convt2d_t4_k<128><<<B * nf * bpc80_128, 128, 0, stream>>>(T40B, wt_up2, bt_up2, T80, B, nf, 40, 40, bpc80_128);
    conv2d_cat_t4_k<128><<<B * nf * bpc80_128, 128, 0, stream>>>(T80, F1, w_up1a, b_up1a, T80B, B, nf, nf, 80, 80, nf, bpc80_128);
    convt2d_t4_k<256><<<B * nf * bpc160, 256, 0, stream>>>(T80B, wt_up1, bt_up1, T160, B, nf, 80, 80, bpc160);

    // --- conv3d_b + relu + mean (streaming) -> F0 ---
    conv3db_k<<<B * 2 * 400, TPB, 0, stream>>>(XA, WT, b_tf3b, F0, B, H, W);
    // FUSED = relu(conv_tf2(MEAN) + T160)
    conv2d_c4_k<1, 1><<<B * 8 * bpc160, TPB, 0, stream>>>(F0, w_tf2, b_tf2, T160, TF, B, nf, 160, 160, nf, 8, bpc160);

    // --- offset/mask head (OM overwrites XA region; XA dead by now) ---
    conv2d_c4_k<1, 0><<<B * 8 * bpc160, TPB, 0, stream>>>(TF, w_out, b_out, nullptr, F0, B, nf, 160, 160, nf, 8, bpc160);
    conv2d_c8_k<0><<<B * 24 * bpc160, TPB, 0, stream>>>(F0, w_om, b_om, OM, B, nf, 160, 160, 189, 24, bpc160);

    // --- deformable conv ---
    dim3 dgrid(nblk((long long)B * H * W), 4);
    deform_conv_k<<<dgrid, TPB, 0, stream>>>(inputs, OM, WT2, b_dc, out, B, H, W);
}

// Round 12
// 980.408 us; speedup vs baseline: 1.0746x; 1.0549x over previous
//
#include <hip/hip_runtime.h>
#include <math.h>

// ---------------------------------------------------------------------------
// STDF forward, round 12: two-phase deformable conv (sampling computed ONCE
// per pixel into LDS, then 16-co FMA phase with scalar weights) — removes the
// 4x om/bilinear redundancy of the co-split. Everything else identical to
// round 11 (verified 1034us).
// ---------------------------------------------------------------------------

#define TPB 256

static inline int nblk(long long total) { return (int)((total + TPB - 1) / TPB); }

// ---------------- 3x3 conv2d, stride 1, 4 outputs/thread, block-uniform co --
template <int TB, int RELU, int HAS_RES>
__global__ __launch_bounds__(TB) void conv2d_t4_k(
    const float* __restrict__ in, const float* __restrict__ w,
    const float* __restrict__ bias, const float* __restrict__ res,
    float* __restrict__ out, int B, int Ci, int H, int W, int Co, int BPC) {
    __shared__ float ws_w[32 * 9];
    int co = (blockIdx.x / BPC) % Co;
    int b  = blockIdx.x / (BPC * Co);
    for (int i = threadIdx.x; i < Ci * 9; i += TB)
        ws_w[i] = w[(size_t)co * Ci * 9 + i];
    __syncthreads();
    int nq = W >> 2;
    int r = (blockIdx.x % BPC) * TB + threadIdx.x;
    if (r >= H * nq) return;
    int q = r % nq, ho = r / nq;
    int wb = q * 4;
    float bv = bias[co];
    float a0 = bv, a1 = bv, a2 = bv, a3 = bv;
    const float* ipb = in + (size_t)b * Ci * H * W;
    for (int ci = 0; ci < Ci; ++ci) {
        const float* ip = ipb + (size_t)ci * H * W;
        const float* wc = ws_w + ci * 9;
#pragma unroll
        for (int kh = 0; kh < 3; ++kh) {
            int y = ho - 1 + kh;
            if (y < 0 || y >= H) continue;
            const float* row = ip + (size_t)y * W + wb;
            float4 xv = *(const float4*)row;
            float xm = (wb > 0) ? row[-1] : 0.f;
            float xp = (wb + 4 < W) ? row[4] : 0.f;
            float w0 = wc[kh * 3], w1 = wc[kh * 3 + 1], w2 = wc[kh * 3 + 2];
            a0 += xm   * w0 + xv.x * w1 + xv.y * w2;
            a1 += xv.x * w0 + xv.y * w1 + xv.z * w2;
            a2 += xv.y * w0 + xv.z * w1 + xv.w * w2;
            a3 += xv.z * w0 + xv.w * w1 + xp   * w2;
        }
    }
    size_t o = ((size_t)(b * Co + co) * H + ho) * W + wb;
    if (HAS_RES) {
        float4 rv = *(const float4*)(res + o);
        a0 += rv.x; a1 += rv.y; a2 += rv.z; a3 += rv.w;
    }
    if (RELU) { a0 = fmaxf(a0, 0.f); a1 = fmaxf(a1, 0.f); a2 = fmaxf(a2, 0.f); a3 = fmaxf(a3, 0.f); }
    *(float4*)(out + o) = make_float4(a0, a1, a2, a3);
}

// ------- 3x3 conv2d, stride 1, 4 outputs x 4 co per thread -----------------
template <int RELU, int HAS_RES>
__global__ __launch_bounds__(TPB) void conv2d_c4_k(
    const float* __restrict__ in, const float* __restrict__ w,
    const float* __restrict__ bias, const float* __restrict__ res,
    float* __restrict__ out, int B, int Ci, int H, int W, int Co, int COG, int BPC) {
    __shared__ float ws_w[4 * 32 * 9];
    int cog = (blockIdx.x / BPC) % COG;
    int b   = blockIdx.x / (BPC * COG);
    int co0 = cog * 4;
    int nw = Ci * 9;
    for (int i = threadIdx.x; i < 4 * nw; i += TPB) {
        int cr = i / nw; int co = co0 + cr;
        ws_w[i] = (co < Co) ? w[(size_t)co * nw + (i - cr * nw)] : 0.f;
    }
    __syncthreads();
    int nq = W >> 2;
    int r = (blockIdx.x % BPC) * TPB + threadIdx.x;
    if (r >= H * nq) return;
    int q = r % nq, ho = r / nq;
    int wb = q * 4;
    float a[4][4];
#pragma unroll
    for (int cr = 0; cr < 4; ++cr) {
        float bv = (co0 + cr < Co) ? bias[co0 + cr] : 0.f;
        a[cr][0] = bv; a[cr][1] = bv; a[cr][2] = bv; a[cr][3] = bv;
    }
    const float* ipb = in + (size_t)b * Ci * H * W;
    for (int ci = 0; ci < Ci; ++ci) {
        const float* ip = ipb + (size_t)ci * H * W;
#pragma unroll
        for (int kh = 0; kh < 3; ++kh) {
            int y = ho - 1 + kh;
            if (y < 0 || y >= H) continue;
            const float* row = ip + (size_t)y * W + wb;
            float4 xv = *(const float4*)row;
            float x_[6];
            x_[0] = (wb > 0) ? row[-1] : 0.f;
            x_[1] = xv.x; x_[2] = xv.y; x_[3] = xv.z; x_[4] = xv.w;
            x_[5] = (wb + 4 < W) ? row[4] : 0.f;
#pragma unroll
            for (int cr = 0; cr < 4; ++cr) {
                const float* wc = ws_w + cr * nw + ci * 9 + kh * 3;
                float w0 = wc[0], w1 = wc[1], w2 = wc[2];
                a[cr][0] += x_[0] * w0 + x_[1] * w1 + x_[2] * w2;
                a[cr][1] += x_[1] * w0 + x_[2] * w1 + x_[3] * w2;
                a[cr][2] += x_[2] * w0 + x_[3] * w1 + x_[4] * w2;
                a[cr][3] += x_[3] * w0 + x_[4] * w1 + x_[5] * w2;
            }
        }
    }
#pragma unroll
    for (int cr = 0; cr < 4; ++cr) {
        int co = co0 + cr;
        if (co >= Co) break;
        size_t o = ((size_t)(b * Co + co) * H + ho) * W + wb;
        float a0 = a[cr][0], a1 = a[cr][1], a2 = a[cr][2], a3 = a[cr][3];
        if (HAS_RES) {
            float4 rv = *(const float4*)(res + o);
            a0 += rv.x; a1 += rv.y; a2 += rv.z; a3 += rv.w;
        }
        if (RELU) { a0 = fmaxf(a0, 0.f); a1 = fmaxf(a1, 0.f); a2 = fmaxf(a2, 0.f); a3 = fmaxf(a3, 0.f); }
        *(float4*)(out + o) = make_float4(a0, a1, a2, a3);
    }
}

// ------- 3x3 conv2d, stride 1, 4 outputs x 8 co per thread (for w_om) ------
template <int RELU>
__global__ __launch_bounds__(TPB) void conv2d_c8_k(
    const float* __restrict__ in, const float* __restrict__ w,
    const float* __restrict__ bias, float* __restrict__ out,
    int B, int Ci, int H, int W, int Co, int COG, int BPC) {
    __shared__ __align__(16) float4 wsa[32 * 9];
    __shared__ __align__(16) float4 wsb[32 * 9];
    int cog = (blockIdx.x / BPC) % COG;
    int b   = blockIdx.x / (BPC * COG);
    int co0 = cog * 8;
    int nw = Ci * 9;
    for (int i = threadIdx.x; i < nw; i += TPB) {
        float4 v, u;
        v.x = (co0 + 0 < Co) ? w[(size_t)(co0 + 0) * nw + i] : 0.f;
        v.y = (co0 + 1 < Co) ? w[(size_t)(co0 + 1) * nw + i] : 0.f;
        v.z = (co0 + 2 < Co) ? w[(size_t)(co0 + 2) * nw + i] : 0.f;
        v.w = (co0 + 3 < Co) ? w[(size_t)(co0 + 3) * nw + i] : 0.f;
        u.x = (co0 + 4 < Co) ? w[(size_t)(co0 + 4) * nw + i] : 0.f;
        u.y = (co0 + 5 < Co) ? w[(size_t)(co0 + 5) * nw + i] : 0.f;
        u.z = (co0 + 6 < Co) ? w[(size_t)(co0 + 6) * nw + i] : 0.f;
        u.w = (co0 + 7 < Co) ? w[(size_t)(co0 + 7) * nw + i] : 0.f;
        wsa[i] = v; wsb[i] = u;
    }
    __syncthreads();
    int nq = W >> 2;
    int r = (blockIdx.x % BPC) * TPB + threadIdx.x;
    if (r >= H * nq) return;
    int q = r % nq, ho = r / nq;
    int wb = q * 4;
    float a[8][4];
#pragma unroll
    for (int cr = 0; cr < 8; ++cr) {
        float bv = (co0 + cr < Co) ? bias[co0 + cr] : 0.f;
        a[cr][0] = bv; a[cr][1] = bv; a[cr][2] = bv; a[cr][3] = bv;
    }
    const float* ipb = in + (size_t)b * Ci * H * W;
    for (int ci = 0; ci < Ci; ++ci) {
        const float* ip = ipb + (size_t)ci * H * W;
#pragma unroll
        for (int kh = 0; kh < 3; ++kh) {
            int y = ho - 1 + kh;
            if (y < 0 || y >= H) continue;
            const float* row = ip + (size_t)y * W + wb;
            float4 xv = *(const float4*)row;
            float x_[6];
            x_[0] = (wb > 0) ? row[-1] : 0.f;
            x_[1] = xv.x; x_[2] = xv.y; x_[3] = xv.z; x_[4] = xv.w;
            x_[5] = (wb + 4 < W) ? row[4] : 0.f;
#pragma unroll
            for (int kw = 0; kw < 3; ++kw) {
                float4 wv = wsa[ci * 9 + kh * 3 + kw];
                float4 wu = wsb[ci * 9 + kh * 3 + kw];
                float x0 = x_[kw], x1 = x_[kw + 1], x2 = x_[kw + 2], x3 = x_[kw + 3];
                a[0][0] += x0 * wv.x; a[0][1] += x1 * wv.x; a[0][2] += x2 * wv.x; a[0][3] += x3 * wv.x;
                a[1][0] += x0 * wv.y; a[1][1] += x1 * wv.y; a[1][2] += x2 * wv.y; a[1][3] += x3 * wv.y;
                a[2][0] += x0 * wv.z; a[2][1] += x1 * wv.z; a[2][2] += x2 * wv.z; a[2][3] += x3 * wv.z;
                a[3][0] += x0 * wv.w; a[3][1] += x1 * wv.w; a[3][2] += x2 * wv.w; a[3][3] += x3 * wv.w;
                a[4][0] += x0 * wu.x; a[4][1] += x1 * wu.x; a[4][2] += x2 * wu.x; a[4][3] += x3 * wu.x;
                a[5][0] += x0 * wu.y; a[5][1] += x1 * wu.y; a[5][2] += x2 * wu.y; a[5][3] += x3 * wu.y;
                a[6][0] += x0 * wu.z; a[6][1] += x1 * wu.z; a[6][2] += x2 * wu.z; a[6][3] += x3 * wu.z;
                a[7][0] += x0 * wu.w; a[7][1] += x1 * wu.w; a[7][2] += x2 * wu.w; a[7][3] += x3 * wu.w;
            }
        }
    }
#pragma unroll
    for (int cr = 0; cr < 8; ++cr) {
        int co = co0 + cr;
        if (co >= Co) break;
        size_t o = ((size_t)(b * Co + co) * H + ho) * W + wb;
        float a0 = a[cr][0], a1 = a[cr][1], a2 = a[cr][2], a3 = a[cr][3];
        if (RELU) { a0 = fmaxf(a0, 0.f); a1 = fmaxf(a1, 0.f); a2 = fmaxf(a2, 0.f); a3 = fmaxf(a3, 0.f); }
        *(float4*)(out + o) = make_float4(a0, a1, a2, a3);
    }
}

// ------------- 3x3 conv2d over concat of two 32-ch inputs, stride 1, relu ---
template <int TB>
__global__ __launch_bounds__(TB) void conv2d_cat_t4_k(
    const float* __restrict__ in1, const float* __restrict__ in2,
    const float* __restrict__ w, const float* __restrict__ bias,
    float* __restrict__ out, int B, int C1, int C2, int H, int W, int Co, int BPC) {
    __shared__ float ws_w[64 * 9];
    int Ci = C1 + C2;
    int co = (blockIdx.x / BPC) % Co;
    int b  = blockIdx.x / (BPC * Co);
    for (int i = threadIdx.x; i < Ci * 9; i += TB)
        ws_w[i] = w[(size_t)co * Ci * 9 + i];
    __syncthreads();
    int nq = W >> 2;
    int r = (blockIdx.x % BPC) * TB + threadIdx.x;
    if (r >= H * nq) return;
    int q = r % nq, ho = r / nq;
    int wb = q * 4;
    float bv = bias[co];
    float a0 = bv, a1 = bv, a2 = bv, a3 = bv;
    for (int ci = 0; ci < Ci; ++ci) {
        const float* ip = (ci < C1)
            ? in1 + ((size_t)(b * C1 + ci)) * H * W
            : in2 + ((size_t)(b * C2 + (ci - C1))) * H * W;
        const float* wc = ws_w + ci * 9;
#pragma unroll
        for (int kh = 0; kh < 3; ++kh) {
            int y = ho - 1 + kh;
            if (y < 0 || y >= H) continue;
            const float* row = ip + (size_t)y * W + wb;
            float4 xv = *(const float4*)row;
            float xm = (wb > 0) ? row[-1] : 0.f;
            float xp = (wb + 4 < W) ? row[4] : 0.f;
            float w0 = wc[kh * 3], w1 = wc[kh * 3 + 1], w2 = wc[kh * 3 + 2];
            a0 += xm   * w0 + xv.x * w1 + xv.y * w2;
            a1 += xv.x * w0 + xv.y * w1 + xv.z * w2;
            a2 += xv.y * w0 + xv.z * w1 + xv.w * w2;
            a3 += xv.z * w0 + xv.w * w1 + xp   * w2;
        }
    }
    size_t o = ((size_t)(b * Co + co) * H + ho) * W + wb;
    *(float4*)(out + o) = make_float4(fmaxf(a0, 0.f), fmaxf(a1, 0.f), fmaxf(a2, 0.f), fmaxf(a3, 0.f));
}

// ------------- 3x3 conv2d, stride 2, 4 outputs/thread, relu ----------------
template <int TB>
__global__ __launch_bounds__(TB) void conv2d_s2_t4_k(
    const float* __restrict__ in, const float* __restrict__ w,
    const float* __restrict__ bias, float* __restrict__ out,
    int B, int Ci, int Hi, int Wi, int Co, int BPC) {
    __shared__ float ws_w[32 * 9];
    int Ho = Hi >> 1, Wo = Wi >> 1;
    int co = (blockIdx.x / BPC) % Co;
    int b  = blockIdx.x / (BPC * Co);
    for (int i = threadIdx.x; i < Ci * 9; i += TB)
        ws_w[i] = w[(size_t)co * Ci * 9 + i];
    __syncthreads();
    int nq = Wo >> 2;
    int r = (blockIdx.x % BPC) * TB + threadIdx.x;
    if (r >= Ho * nq) return;
    int q = r % nq, ho = r / nq;
    int wb = q * 4;
    float bv = bias[co];
    float a0 = bv, a1 = bv, a2 = bv, a3 = bv;
    const float* ipb = in + (size_t)b * Ci * Hi * Wi;
    for (int ci = 0; ci < Ci; ++ci) {
        const float* ip = ipb + (size_t)ci * Hi * Wi;
        const float* wc = ws_w + ci * 9;
#pragma unroll
        for (int kh = 0; kh < 3; ++kh) {
            int y = 2 * ho - 1 + kh;
            if (y < 0 || y >= Hi) continue;
            const float* row = ip + (size_t)y * Wi;
            float z0 = (2 * wb - 1 >= 0) ? row[2 * wb - 1] : 0.f;
            float4 za = *(const float4*)(row + 2 * wb);
            float4 zb = *(const float4*)(row + 2 * wb + 4);
            float w0 = wc[kh * 3], w1 = wc[kh * 3 + 1], w2 = wc[kh * 3 + 2];
            a0 += z0   * w0 + za.x * w1 + za.y * w2;
            a1 += za.y * w0 + za.z * w1 + za.w * w2;
            a2 += za.w * w0 + zb.x * w1 + zb.y * w2;
            a3 += zb.y * w0 + zb.z * w1 + zb.w * w2;
        }
    }
    size_t o = ((size_t)(b * Co + co) * Ho + ho) * Wo + wb;
    *(float4*)(out + o) = make_float4(fmaxf(a0, 0.f), fmaxf(a1, 0.f), fmaxf(a2, 0.f), fmaxf(a3, 0.f));
}

// ------------- transposed conv 4x4 stride 2, 4 outputs/thread, relu --------
template <int TB>
__global__ __launch_bounds__(TB) void convt2d_t4_k(
    const float* __restrict__ in, const float* __restrict__ wt,
    const float* __restrict__ bias, float* __restrict__ out,
    int B, int C, int Hi, int Wi, int BPC) {
    __shared__ float ws_w[32 * 16];
    int Ho = 2 * Hi, Wo = 2 * Wi;
    int co = (blockIdx.x / BPC) % C;
    int b  = blockIdx.x / (BPC * C);
    for (int i = threadIdx.x; i < C * 16; i += TB) {
        int ci = i >> 4, t = i & 15;
        ws_w[i] = wt[((size_t)ci * C + co) * 16 + t];
    }
    __syncthreads();
    int nq = Wo >> 2;
    int r = (blockIdx.x % BPC) * TB + threadIdx.x;
    if (r >= Ho * nq) return;
    int q = r % nq, ho = r / nq;
    int wb = q * 4;
    int p = ho & 1;
    int iy0 = (ho + p) / 2 - 1;
    int iy1 = iy0 + 1;
    int ix0 = wb / 2 - 1;
    bool vy0 = (iy0 >= 0) && (iy0 < Hi);
    bool vy1 = (iy1 >= 0) && (iy1 < Hi);
    float bv = bias[co];
    float a0 = bv, a1 = bv, a2 = bv, a3 = bv;
    const float* ipb = in + (size_t)b * C * Hi * Wi;
    for (int ci = 0; ci < C; ++ci) {
        const float* ip = ipb + (size_t)ci * Hi * Wi;
        float u0 = 0, u1 = 0, u2 = 0, u3 = 0, v0 = 0, v1 = 0, v2 = 0, v3 = 0;
        if (vy0) {
            const float* rw = ip + (size_t)iy0 * Wi;
            if (ix0 >= 0) u0 = rw[ix0];
            u1 = rw[ix0 + 1]; u2 = rw[ix0 + 2];
            if (ix0 + 3 < Wi) u3 = rw[ix0 + 3];
        }
        if (vy1) {
            const float* rw = ip + (size_t)iy1 * Wi;
            if (ix0 >= 0) v0 = rw[ix0];
            v1 = rw[ix0 + 1]; v2 = rw[ix0 + 2];
            if (ix0 + 3 < Wi) v3 = rw[ix0 + 3];
        }
        const float* wr0 = ws_w + ci * 16 + (3 - p) * 4;
        const float* wr1 = ws_w + ci * 16 + (1 - p) * 4;
        a0 += u0 * wr0[3] + u1 * wr0[1] + v0 * wr1[3] + v1 * wr1[1];
        a1 += u1 * wr0[2] + u2 * wr0[0] + v1 * wr1[2] + v2 * wr1[0];
        a2 += u1 * wr0[3] + u2 * wr0[1] + v1 * wr1[3] + v2 * wr1[1];
        a3 += u2 * wr0[2] + u3 * wr0[0] + v2 * wr1[2] + v3 * wr1[0];
    }
    size_t o = ((size_t)(b * C + co) * Ho + ho) * Wo + wb;
    *(float4*)(out + o) = make_float4(fmaxf(a0, 0.f), fmaxf(a1, 0.f), fmaxf(a2, 0.f), fmaxf(a3, 0.f));
}

// ---- merged prep: wb transpose + wdc transpose + xa border zero -------------
__global__ void prep_k(const float* __restrict__ wb, const float* __restrict__ wdc,
                       float* __restrict__ wt, float* __restrict__ wt2,
                       float* __restrict__ xa_g) {
    int i = blockIdx.x * TPB + threadIdx.x;
    if (i < 27648) {
        int kd = i % 3; int t = i / 3;
        int co = t % 32; t /= 32;
        int j  = t % 9;  int ci = t / 9;
        wt[i] = wb[(size_t)(co * 32 + ci) * 27 + kd * 9 + j];
        return;
    }
    int i2 = i - 27648;
    if (i2 < 4032) {
        int o = i2 & 63, ck = i2 >> 6;
        wt2[i2] = wdc[o * 63 + ck];
        return;
    }
    int i3 = i2 - 4032;
    if (i3 >= 448 * 644) return;
    int pl = i3 / 644, e = i3 % 644;
    int off;
    if (e < 162)      off = e;
    else if (e < 324) off = 161 * 162 + (e - 162);
    else if (e < 484) off = (e - 324 + 1) * 162;
    else              off = (e - 484 + 1) * 162 + 161;
    xa_g[(size_t)pl * 26244 + off] = 0.f;
}

// ---- conv3d_a: x (B,7,H,W) -> relu -> padded xa [B][32][7][162][162] -------
__global__ __launch_bounds__(TPB) void conv3da_k(
    const float* __restrict__ x, const float* __restrict__ wa,
    const float* __restrict__ ba, float* __restrict__ xa_g,
    int B, int H, int W) {
    __shared__ float w27[27];
    int blk = blockIdx.x;
    int t5 = blk % 25; int rest = blk / 25;
    int d = rest % 7; rest /= 7;
    int co = rest % 32; int b = rest / 32;
    if (threadIdx.x < 27) w27[threadIdx.x] = wa[co * 27 + threadIdx.x];
    __syncthreads();
    int r = t5 * TPB + threadIdx.x;
    if (r >= 160 * 40) return;
    int y = r / 40, x0 = (r % 40) * 4;
    float bv = ba[co];
    float a0 = bv, a1 = bv, a2 = bv, a3 = bv;
#pragma unroll
    for (int kd = 0; kd < 3; ++kd) {
        int dz = d + kd - 1;
        if (dz < 0 || dz >= 7) continue;
        const float* pl = x + ((size_t)(b * 7 + dz)) * H * W;
#pragma unroll
        for (int kh = 0; kh < 3; ++kh) {
            int yy = y + kh - 1;
            if (yy < 0 || yy >= H) continue;
            const float* row = pl + (size_t)yy * W + x0;
            float4 xv = *(const float4*)row;
            float xm = (x0 > 0) ? row[-1] : 0.f;
            float xp = (x0 + 4 < W) ? row[4] : 0.f;
            float w0 = w27[kd * 9 + kh * 3], w1 = w27[kd * 9 + kh * 3 + 1], w2 = w27[kd * 9 + kh * 3 + 2];
            a0 += xm   * w0 + xv.x * w1 + xv.y * w2;
            a1 += xv.x * w0 + xv.y * w1 + xv.z * w2;
            a2 += xv.y * w0 + xv.z * w1 + xv.w * w2;
            a3 += xv.z * w0 + xv.w * w1 + xp   * w2;
        }
    }
    size_t base = ((size_t)((b * 32 + co) * 7 + d)) * 26244 + (size_t)(y + 1) * 162 + (x0 + 1);
    xa_g[base + 0] = fmaxf(a0, 0.f);
    xa_g[base + 1] = fmaxf(a1, 0.f);
    xa_g[base + 2] = fmaxf(a2, 0.f);
    xa_g[base + 3] = fmaxf(a3, 0.f);
}

// ---- conv3d_b + relu + mean, streaming xa from global (verified) -----------
__global__ __launch_bounds__(TPB) void conv3db_k(
    const float* __restrict__ xa_g, const float* __restrict__ wt,
    const float* __restrict__ bb, float* __restrict__ out,
    int B, int H, int W) {
    __shared__ float xab[2][840];
    const int PLANE = 26244, CI_S = 183708, B_S = 5878656;
    const int RS = 12, DS = 120;
    int tile = blockIdx.x % 400;
    int half = (blockIdx.x / 400) & 1;
    int b = blockIdx.x / 800;
    int bx = tile % 20, by = tile / 20;
    int h0 = by * 8, w0 = bx * 8;
    int tid = threadIdx.x;
    int p = tid & 63; int px = p & 7; int py = p >> 3;
    int g = tid >> 6;

    int gu = __builtin_amdgcn_readfirstlane(g);
    const float* wbase = wt + half * 48 + gu * 12;

    int it0 = tid, it1 = tid + 256, it2 = tid + 512;
    bool h2 = (it2 < 700);
    int dd0 = it0 / 100, rm0 = it0 % 100;
    int xo0 = dd0 * PLANE + (h0 + rm0 / 10) * 162 + (w0 + rm0 % 10);
    int lo0 = dd0 * DS + (rm0 / 10) * RS + rm0 % 10;
    int dd1 = it1 / 100, rm1 = it1 % 100;
    int xo1 = dd1 * PLANE + (h0 + rm1 / 10) * 162 + (w0 + rm1 % 10);
    int lo1 = dd1 * DS + (rm1 / 10) * RS + rm1 % 10;
    int xo2 = 0, lo2 = 0;
    if (h2) {
        int dd2 = it2 / 100, rm2 = it2 % 100;
        xo2 = dd2 * PLANE + (h0 + rm2 / 10) * 162 + (w0 + rm2 % 10);
        lo2 = dd2 * DS + (rm2 / 10) * RS + rm2 % 10;
    }

    const float* xbase = xa_g + (size_t)b * B_S;

    float acc[4][7];
#pragma unroll
    for (int r = 0; r < 4; ++r) {
        float bv = bb[half * 16 + g * 4 + r];
#pragma unroll
        for (int d = 0; d < 7; ++d) acc[r][d] = bv;
    }

    {
        float r0 = xbase[xo0], r1 = xbase[xo1], r2 = h2 ? xbase[xo2] : 0.f;
        xab[0][lo0] = r0; xab[0][lo1] = r1; if (h2) xab[0][lo2] = r2;
    }
    __syncthreads();

    for (int ci = 0; ci < 32; ++ci) {
        int cur = ci & 1, nxt = cur ^ 1;
        bool more = (ci + 1 < 32);
        float r0 = 0.f, r1 = 0.f, r2 = 0.f;
        if (more) {
            const float* xs = xbase + (size_t)(ci + 1) * CI_S;
            r0 = xs[xo0]; r1 = xs[xo1]; r2 = h2 ? xs[xo2] : 0.f;
        }
        const float* xab_c = xab[cur];
        const float* wci = wbase + (size_t)ci * 864;
#pragma unroll
        for (int kh = 0; kh < 3; ++kh) {
#pragma unroll
            for (int kw = 0; kw < 3; ++kw) {
                int j = kh * 3 + kw;
                float xav[7];
                const float* xb = xab_c + (py + kh) * RS + (px + kw);
#pragma unroll
                for (int d = 0; d < 7; ++d) xav[d] = xb[d * DS];
                const float4* wp = (const float4*)(wci + j * 96);
                float4 w0 = wp[0], w1 = wp[1], w2 = wp[2];
                float wr[4][3] = {{w0.x, w0.y, w0.z}, {w0.w, w1.x, w1.y},
                                  {w1.z, w1.w, w2.x}, {w2.y, w2.z, w2.w}};
#pragma unroll
                for (int r = 0; r < 4; ++r) {
#pragma unroll
                    for (int d = 1; d < 7; ++d) acc[r][d] += xav[d - 1] * wr[r][0];
#pragma unroll
                    for (int d = 0; d < 7; ++d) acc[r][d] += xav[d] * wr[r][1];
#pragma unroll
                    for (int d = 0; d < 6; ++d) acc[r][d] += xav[d + 1] * wr[r][2];
                }
            }
        }
        if (more) {
            xab[nxt][lo0] = r0; xab[nxt][lo1] = r1; if (h2) xab[nxt][lo2] = r2;
        }
        __syncthreads();
    }

    size_t HW = (size_t)H * W;
#pragma unroll
    for (int r = 0; r < 4; ++r) {
        float s = 0.f;
#pragma unroll
        for (int d = 0; d < 7; ++d) s += fmaxf(acc[r][d], 0.f);
        int co = half * 16 + g * 4 + r;
        out[((size_t)(b * 32 + co)) * HW + (size_t)(h0 + py) * W + (w0 + px)] = s * (1.f / 7.f);
    }
}

// ------------- two-phase modulated deformable conv ---------------------------
// Phase 1: 256 threads compute all 64px x 63tap sampled*masked values -> LDS.
// Phase 2: thread (pxl, cogroup of 16): 63 LDS broadcasts + 1008 FMA with
// wave-uniform scalar weights. grid = B*H*W/64 blocks.
__global__ __launch_bounds__(TPB) void deform_conv2_k(
    const float* __restrict__ x, const float* __restrict__ om,
    const float* __restrict__ wt2, const float* __restrict__ bias,
    float* __restrict__ out, int B, int H, int W) {
    __shared__ float smp[63 * 64];
    const int HW = H * W;
    int blk = blockIdx.x;
    int b = blk / (HW / 64);
    int pxbase = (blk % (HW / 64)) * 64;
    int tid = threadIdx.x;
    const float* omb = om + (size_t)b * 189 * HW;
    const float* xb = x + (size_t)b * 7 * HW;

    // phase 1: sampling (4032 items, 16 rounds)
#pragma unroll 4
    for (int k = 0; k < 16; ++k) {
        int it = tid + k * 256;
        if (it >= 4032) break;
        int pxl = it & 63;
        int tap = it >> 6;
        int c = tap / 9, kk = tap % 9;
        int hw = pxbase + pxl;
        int hq = hw / W, wq = hw % W;
        float dy = omb[(size_t)(c * 18 + kk * 2 + 0) * HW + hw];
        float dx = omb[(size_t)(c * 18 + kk * 2 + 1) * HW + hw];
        float mv = omb[(size_t)(126 + c * 9 + kk) * HW + hw];
        float m = 1.f / (1.f + __expf(-mv));
        float py = (float)hq + (float)(kk / 3 - 1) + dy;
        float px = (float)wq + (float)(kk % 3 - 1) + dx;
        float y0f = floorf(py), x0f = floorf(px);
        int y0 = (int)y0f, x0 = (int)x0f;
        float wy1 = py - y0f, wx1 = px - x0f;
        float wy0 = 1.f - wy1, wx0 = 1.f - wx1;
        float v00 = 0.f, v01 = 0.f, v10 = 0.f, v11 = 0.f;
        const float* xc = xb + (size_t)c * HW;
        bool yin0 = (y0 >= 0) & (y0 < H);
        bool yin1 = (y0 + 1 >= 0) & (y0 + 1 < H);
        bool xin0 = (x0 >= 0) & (x0 < W);
        bool xin1 = (x0 + 1 >= 0) & (x0 + 1 < W);
        if (yin0) {
            const float* rr = xc + (size_t)y0 * W;
            if (xin0) v00 = rr[x0];
            if (xin1) v01 = rr[x0 + 1];
        }
        if (yin1) {
            const float* rr = xc + (size_t)(y0 + 1) * W;
            if (xin0) v10 = rr[x0];
            if (xin1) v11 = rr[x0 + 1];
        }
        smp[tap * 64 + pxl] =
            (wy0 * wx0 * v00 + wy0 * wx1 * v01 + wy1 * wx0 * v10 + wy1 * wx1 * v11) * m;
    }
    __syncthreads();

    // phase 2: 16 co per thread, scalar weights
    int pxl = tid & 63;
    int g = tid >> 6;
    int gu = __builtin_amdgcn_readfirstlane(g);
    const float* swb = wt2 + gu * 16;
    const float* bsb = bias + gu * 16;
    float acc[16];
#pragma unroll
    for (int o = 0; o < 16; ++o) acc[o] = 0.f;
    for (int tap = 0; tap < 63; ++tap) {
        float s = smp[tap * 64 + pxl];
        const float* sw = swb + tap * 64;
#pragma unroll
        for (int o = 0; o < 16; ++o) acc[o] += s * sw[o];
    }
    int hw = pxbase + pxl;
    size_t obase = (size_t)b * 64 * HW + (size_t)gu * 16 * HW + hw;
#pragma unroll
    for (int o = 0; o < 16; ++o)
        out[obase + (size_t)o * HW] = fmaxf(acc[o] + bsb[o], 0.f);
}

extern "C" void kernel_launch(void* const* d_in, const int* in_sizes, int n_in,
                              void* d_out, int out_size, void* d_ws, size_t ws_size,
                              hipStream_t stream) {
    (void)in_sizes; (void)n_in; (void)out_size; (void)ws_size;
    const float* inputs = (const float*)d_in[0];
    const float* w_in   = (const float*)d_in[1];  const float* b_in   = (const float*)d_in[2];
    const float* w_dn1a = (const float*)d_in[3];  const float* b_dn1a = (const float*)d_in[4];
    const float* w_dn1b = (const float*)d_in[5];  const float* b_dn1b = (const float*)d_in[6];
    const float* w_up1a = (const float*)d_in[7];  const float* b_up1a = (const float*)d_in[8];
    const float* wt_up1 = (const float*)d_in[9];  const float* bt_up1 = (const float*)d_in[10];
    const float* w_dn2a = (const float*)d_in[11]; const float* b_dn2a = (const float*)d_in[12];
    const float* w_dn2b = (const float*)d_in[13]; const float* b_dn2b = (const float*)d_in[14];
    const float* w_up2a = (const float*)d_in[15]; const float* b_up2a = (const float*)d_in[16];
    const float* wt_up2 = (const float*)d_in[17]; const float* bt_up2 = (const float*)d_in[18];
    const float* w_tra  = (const float*)d_in[19]; const float* b_tra  = (const float*)d_in[20];
    const float* w_trb  = (const float*)d_in[21]; const float* b_trb  = (const float*)d_in[22];
    const float* wt_tr  = (const float*)d_in[23]; const float* bt_tr  = (const float*)d_in[24];
    const float* w_out  = (const float*)d_in[25]; const float* b_out  = (const float*)d_in[26];
    const float* w_tf3a = (const float*)d_in[27]; const float* b_tf3a = (const float*)d_in[28];
    const float* w_tf3b = (const float*)d_in[29]; const float* b_tf3b = (const float*)d_in[30];
    const float* w_tf2  = (const float*)d_in[31]; const float* b_tf2  = (const float*)d_in[32];
    const float* w_om   = (const float*)d_in[33]; const float* b_om   = (const float*)d_in[34];
    const float* w_dc   = (const float*)d_in[35]; const float* b_dc   = (const float*)d_in[36];
    float* out = (float*)d_out;

    const int B = 2, nf = 32, H = 160, W = 160;
    const size_t n160 = (size_t)B * nf * 160 * 160;
    const size_t n80  = (size_t)B * nf * 80 * 80;
    const size_t n40  = (size_t)B * nf * 40 * 40;
    const size_t n20  = (size_t)B * nf * 20 * 20;

    float* ws = (float*)d_ws;
    float* F0    = ws;
    float* TMP80 = F0 + n160;
    float* F1    = TMP80 + n80;
    float* TMP40 = F1 + n80;
    float* F2    = TMP40 + n40;
    float* T20A  = F2 + n40;
    float* T20B  = T20A + n20;
    float* T40   = T20B + n20;
    float* T40B  = T40 + n40;
    float* T80   = T40B + n40;
    float* T80B  = T80 + n80;
    float* T160  = T80B + n80;
    float* TF    = T160 + n160;
    float* XA    = TF + n160;
    float* OM    = XA;                 // ALIAS: OM written after XA is dead
    float* WT    = XA + (size_t)2 * 32 * 7 * 162 * 162;
    float* WT2   = WT + 32 * 9 * 32 * 3;

    const int bpc160 = 25;            // ceil(160*40/256)
    const int bpc80_128 = 13;         // ceil(80*20/128)
    const int bpc40_64  = 7;          // ceil(40*10/64)
    const int bpc20_64  = 2;          // ceil(20*5/64)

    // prep (merged) + conv_a
    prep_k<<<nblk(27648 + 4032 + 448 * 644), TPB, 0, stream>>>(w_tf3b, w_dc, WT, WT2, XA);
    conv3da_k<<<B * 32 * 7 * 25, TPB, 0, stream>>>(inputs, w_tf3a, b_tf3a, XA, B, H, W);

    // --- 2D U-Net branch ---
    conv2d_c4_k<1, 0><<<B * 8 * bpc160, TPB, 0, stream>>>(inputs, w_in, b_in, nullptr, F0, B, 7, 160, 160, nf, 8, bpc160);
    conv2d_s2_t4_k<128><<<B * nf * bpc80_128, 128, 0, stream>>>(F0, w_dn1a, b_dn1a, TMP80, B, nf, 160, 160, nf, bpc80_128);
    conv2d_t4_k<128, 1, 0><<<B * nf * bpc80_128, 128, 0, stream>>>(TMP80, w_dn1b, b_dn1b, nullptr, F1, B, nf, 80, 80, nf, bpc80_128);
    conv2d_s2_t4_k<64><<<B * nf * bpc40_64, 64, 0, stream>>>(F1, w_dn2a, b_dn2a, TMP40, B, nf, 80, 80, nf, bpc40_64);
    conv2d_t4_k<64, 1, 0><<<B * nf * bpc40_64, 64, 0, stream>>>(TMP40, w_dn2b, b_dn2b, nullptr, F2, B, nf, 40, 40, nf, bpc40_64);
    conv2d_s2_t4_k<64><<<B * nf * bpc20_64, 64, 0, stream>>>(F2, w_tra, b_tra, T20A, B, nf, 40, 40, nf, bpc20_64);
    conv2d_t4_k<64, 1, 0><<<B * nf * bpc20_64, 64, 0, stream>>>(T20A, w_trb, b_trb, nullptr, T20B, B, nf, 20, 20, nf, bpc20_64);
    convt2d_t4_k<64><<<B * nf * bpc40_64, 64, 0, stream>>>(T20B, wt_tr, bt_tr, T40, B, nf, 20, 20, bpc40_64);
    conv2d_cat_t4_k<64><<<B * nf * bpc40_64, 64, 0, stream>>>(T40, F2, w_up2a, b_up2a, T40B, B, nf, nf, 40, 40, nf, bpc40_64);
    convt2d_t4_k<128><<<B * nf * bpc80_128, 128, 0, stream>>>(T40B, wt_up2, bt_up2, T80, B, nf, 40, 40, bpc80_128);
    conv2d_cat_t4_k<128><<<B * nf * bpc80_128, 128, 0, stream>>>(T80, F1, w_up1a, b_up1a, T80B, B, nf, nf, 80, 80, nf, bpc80_128);
    convt2d_t4_k<256><<<B * nf * bpc160, 256, 0, stream>>>(T80B, wt_up1, bt_up1, T160, B, nf, 80, 80, bpc160);

    // --- conv3d_b + relu + mean (streaming) -> F0 ---
    conv3db_k<<<B * 2 * 400, TPB, 0, stream>>>(XA, WT, b_tf3b, F0, B, H, W);
    // FUSED = relu(conv_tf2(MEAN) + T160)
    conv2d_c4_k<1, 1><<<B * 8 * bpc160, TPB, 0, stream>>>(F0, w_tf2, b_tf2, T160, TF, B, nf, 160, 160, nf, 8, bpc160);

    // --- offset/mask head (OM overwrites XA region; XA dead by now) ---
    conv2d_c4_k<1, 0><<<B * 8 * bpc160, TPB, 0, stream>>>(TF, w_out, b_out, nullptr, F0, B, nf, 160, 160, nf, 8, bpc160);
    conv2d_c8_k<0><<<B * 24 * bpc160, TPB, 0, stream>>>(F0, w_om, b_om, OM, B, nf, 160, 160, 189, 24, bpc160);

    // --- deformable conv (two-phase) ---
    deform_conv2_k<<<B * (H * W / 64), TPB, 0, stream>>>(inputs, OM, WT2, b_dc, out, B, H, W);
}